// Round 2
// baseline (5041.714 us; speedup 1.0000x reference)
//
#include <hip/hip_runtime.h>
#include <math.h>

#define C_DIM 192
#define HW_ 3136
#define IMG 56
#define NTOK 50176
#define CONV_OUT_SZ 4816896  /* 16*96*3136 */

#define AM_PLAIN 0
#define AM_PATCH 1
#define AM_CONV  2
#define EP_STORE 0
#define EP_GELU  1
#define EP_ADD   2
#define EP_BN_NHWC 3
#define EP_BN_NCHW 4

// ---------------------------------------------------------------------------
// Generic 64x64 tiled fp32 GEMM:  C[m,n] = epi( sum_k A[m,k]*W[n,k] + bias[n] )
// AMODE selects how the A tile is gathered; EPI selects the epilogue.
// M and (except conv2) N are multiples of 64; K is a multiple of 16.
// ---------------------------------------------------------------------------
template<int AMODE, int EPI, bool NG>
__global__ __launch_bounds__(256) void gemm_k(
    const float* __restrict__ A, const float* __restrict__ W,
    const float* __restrict__ bias, float* __restrict__ Cout,
    int M, int N, int K,
    const float* __restrict__ bn_g, const float* __restrict__ bn_b,
    const float* __restrict__ bn_m, const float* __restrict__ bn_v)
{
  __shared__ float As[16][68];
  __shared__ float Ws[16][68];
  const int m0 = blockIdx.x * 64;
  const int n0 = blockIdx.y * 64;
  const int tid = threadIdx.x;
  const int tn = tid & 15, tm = tid >> 4;
  float acc[4][4] = {};
  const int nK = K / 16;
  for (int kc = 0; kc < nK; ++kc) {
    const int k0 = kc * 16;
    // ---- stage A tile (64 rows x 16 k) into As[k][m]
    if (AMODE == AM_PLAIN) {
      const int r = tid >> 2, kk = (tid & 3) * 4;
      const float4 v = *(const float4*)(A + (size_t)(m0 + r) * K + k0 + kk);
      As[kk+0][r] = v.x; As[kk+1][r] = v.y; As[kk+2][r] = v.z; As[kk+3][r] = v.w;
    } else if (AMODE == AM_PATCH) {
      // A[m,k] = x[b, k, p]  (NCHW gather), b = m/HW, p = m%HW
      #pragma unroll
      for (int it = 0; it < 4; ++it) {
        const int id = tid + it * 256;
        const int k = id >> 6, r = id & 63;
        const int m = m0 + r;
        const int b = m / HW_, pp = m - b * HW_;
        As[k][r] = A[(size_t)b * (C_DIM * HW_) + (size_t)(k0 + k) * HW_ + pp];
      }
    } else { // AM_CONV: A[m,(s,ic)] = in_nhwc[b, y+dy, x+dx, ic], zero-padded
      const int r = tid >> 2, kk = (tid & 3) * 4;
      const int s = k0 / C_DIM;
      const int ic = k0 - s * C_DIM + kk;
      const int dy = s / 3 - 1, dx = s % 3 - 1;
      const int m = m0 + r;
      const int b = m / HW_, pp = m - b * HW_;
      const int yy = pp / IMG + dy, xx = pp - (pp / IMG) * IMG + dx;
      float4 v = make_float4(0.f, 0.f, 0.f, 0.f);
      if ((unsigned)yy < IMG && (unsigned)xx < IMG)
        v = *(const float4*)(A + ((size_t)b * HW_ + yy * IMG + xx) * C_DIM + ic);
      As[kk+0][r] = v.x; As[kk+1][r] = v.y; As[kk+2][r] = v.z; As[kk+3][r] = v.w;
    }
    // ---- stage W tile (64 n x 16 k) into Ws[k][n]
    if (AMODE == AM_CONV) {
      // W[n,(s,ic)] = w[n, ic, s] with layout (OC, IC, 3, 3) -> stride 9 over ic
      const int r = tid >> 2, kk = (tid & 3) * 4;
      const int n = n0 + r;
      const int s = k0 / C_DIM;
      const int ic = k0 - s * C_DIM + kk;
      float4 v = make_float4(0.f, 0.f, 0.f, 0.f);
      if (!NG || n < N) {
        const float* wp = W + ((size_t)n * C_DIM + ic) * 9 + s;
        v.x = wp[0]; v.y = wp[9]; v.z = wp[18]; v.w = wp[27];
      }
      Ws[kk+0][r] = v.x; Ws[kk+1][r] = v.y; Ws[kk+2][r] = v.z; Ws[kk+3][r] = v.w;
    } else {
      const int r = tid >> 2, kk = (tid & 3) * 4;
      float4 v = make_float4(0.f, 0.f, 0.f, 0.f);
      if (!NG || (n0 + r) < N)
        v = *(const float4*)(W + (size_t)(n0 + r) * K + k0 + kk);
      Ws[kk+0][r] = v.x; Ws[kk+1][r] = v.y; Ws[kk+2][r] = v.z; Ws[kk+3][r] = v.w;
    }
    __syncthreads();
    #pragma unroll
    for (int k = 0; k < 16; ++k) {
      float a4[4], b4[4];
      *(float4*)a4 = *(const float4*)&As[k][tm * 4];
      *(float4*)b4 = *(const float4*)&Ws[k][tn * 4];
      #pragma unroll
      for (int i = 0; i < 4; ++i)
        #pragma unroll
        for (int j = 0; j < 4; ++j)
          acc[i][j] = fmaf(a4[i], b4[j], acc[i][j]);
    }
    __syncthreads();
  }
  // ---- epilogue
  #pragma unroll
  for (int i = 0; i < 4; ++i) {
    const int m = m0 + tm * 4 + i;
    if (EPI == EP_BN_NCHW) {
      const int b = m / HW_, pp = m - b * HW_;
      #pragma unroll
      for (int j = 0; j < 4; ++j) {
        const int n = n0 + tn * 4 + j;
        if (NG && n >= N) continue;
        float val = acc[i][j] + bias[n];
        val = (val - bn_m[n]) * rsqrtf(bn_v[n] + 1e-5f) * bn_g[n] + bn_b[n];
        Cout[((size_t)b * N + n) * HW_ + pp] = fmaxf(val, 0.f);
      }
    } else {
      float tmp[4];
      #pragma unroll
      for (int j = 0; j < 4; ++j) {
        const int n = n0 + tn * 4 + j;
        float val = acc[i][j] + bias[n];
        if (EPI == EP_GELU) val = 0.5f * val * (1.f + erff(val * 0.70710678118f));
        if (EPI == EP_BN_NHWC) {
          val = (val - bn_m[n]) * rsqrtf(bn_v[n] + 1e-5f) * bn_g[n] + bn_b[n];
          val = fmaxf(val, 0.f);
        }
        tmp[j] = val;
      }
      float* dst = Cout + (size_t)m * N + n0 + tn * 4;
      if (EPI == EP_ADD) {
        const float4 old = *(const float4*)dst;
        tmp[0] += old.x; tmp[1] += old.y; tmp[2] += old.z; tmp[3] += old.w;
      }
      float4 v; v.x = tmp[0]; v.y = tmp[1]; v.z = tmp[2]; v.w = tmp[3];
      *(float4*)dst = v;
    }
  }
}

// ---------------------------------------------------------------------------
// LayerNorm over C=192, wave-per-token (4 tokens/block).
// winpart=1: also apply roll(-shift) and scatter to window-partitioned layout.
// pos != nullptr: add positional embedding (patch-embed LN).
// ---------------------------------------------------------------------------
__global__ __launch_bounds__(256) void ln_k(
    const float* __restrict__ in, float* __restrict__ outp,
    const float* __restrict__ g, const float* __restrict__ bta,
    const float* __restrict__ pos, int winpart, int shift)
{
  const int t = blockIdx.x * 4 + (threadIdx.x >> 6);
  const int lane = threadIdx.x & 63;
  const float* xr = in + (size_t)t * C_DIM;
  const float v0 = xr[lane], v1 = xr[lane + 64], v2 = xr[lane + 128];
  float s = v0 + v1 + v2;
  float ss = v0 * v0 + v1 * v1 + v2 * v2;
  #pragma unroll
  for (int off = 32; off > 0; off >>= 1) {
    s += __shfl_xor(s, off);
    ss += __shfl_xor(ss, off);
  }
  const float mean = s * (1.f / 192.f);
  const float inv = rsqrtf(ss * (1.f / 192.f) - mean * mean + 1e-5f);
  const int b = t / HW_, pp = t - b * HW_;
  size_t obase;
  if (winpart) {
    const int y = pp / IMG, x = pp - (pp / IMG) * IMG;
    int yr = y - shift; if (yr < 0) yr += IMG;
    int xs = x - shift; if (xs < 0) xs += IMG;
    const int win = b * 64 + (yr / 7) * 8 + (xs / 7);
    const int within = (yr % 7) * 7 + (xs % 7);
    obase = ((size_t)win * 49 + within) * C_DIM;
  } else {
    obase = (size_t)t * C_DIM;
  }
  float* o = outp + obase;
  float p0 = 0.f, p1 = 0.f, p2 = 0.f;
  if (pos) {
    const float* pr = pos + (size_t)pp * C_DIM;
    p0 = pr[lane]; p1 = pr[lane + 64]; p2 = pr[lane + 128];
  }
  o[lane]       = (v0 - mean) * inv * g[lane]       + bta[lane]       + p0;
  o[lane + 64]  = (v1 - mean) * inv * g[lane + 64]  + bta[lane + 64]  + p1;
  o[lane + 128] = (v2 - mean) * inv * g[lane + 128] + bta[lane + 128] + p2;
}

// ---------------------------------------------------------------------------
// Window attention: one block per (window-in-chunk, head).
// qkv: (256 windows, 49, 576) for this chunk. Writes (token,192) windowed.
// ---------------------------------------------------------------------------
__global__ __launch_bounds__(256) void attn_k(
    const float* __restrict__ qkv, float* __restrict__ outp,
    const float* __restrict__ rel, int shift, int chunk)
{
  __shared__ float q[49][25], kk[49][25], vv[49][25];
  __shared__ float s[49][50];
  const int h = blockIdx.x & 7;
  const int wid = blockIdx.x >> 3;
  const int tid = threadIdx.x;
  const float* base = qkv + (size_t)wid * 49 * 576 + h * 24;
  for (int id = tid; id < 49 * 24; id += 256) {
    const int i = id / 24, d = id - (id / 24) * 24;
    q[i][d]  = base[i * 576 + d] * 0.20412414523193154f; // HD^-0.5
    kk[i][d] = base[i * 576 + 192 + d];
    vv[i][d] = base[i * 576 + 384 + d];
  }
  __syncthreads();
  const int wb = (chunk * 256 + wid) & 63;
  const int hblk = wb >> 3, wblk = wb & 7;
  for (int id = tid; id < 49 * 49; id += 256) {
    const int i = id / 49, j = id - (id / 49) * 49;
    float acc = 0.f;
    #pragma unroll
    for (int d = 0; d < 24; ++d) acc = fmaf(q[i][d], kk[j][d], acc);
    const int r1 = i / 7, c1 = i - r1 * 7, r2 = j / 7, c2 = j - r2 * 7;
    acc += rel[((r1 - r2 + 6) * 13 + (c1 - c2 + 6)) * 8 + h];
    if (shift) {
      const int hi = hblk * 7 + r1, wi = wblk * 7 + c1;
      const int hj = hblk * 7 + r2, wj = wblk * 7 + c2;
      const int ri = (hi < 49 ? 0 : (hi < 53 ? 1 : 2)) * 3 + (wi < 49 ? 0 : (wi < 53 ? 1 : 2));
      const int rj = (hj < 49 ? 0 : (hj < 53 ? 1 : 2)) * 3 + (wj < 49 ? 0 : (wj < 53 ? 1 : 2));
      if (ri != rj) acc -= 100.f;
    }
    s[i][j] = acc;
  }
  __syncthreads();
  if (tid < 49) {
    float mx = -1e30f;
    for (int j = 0; j < 49; ++j) mx = fmaxf(mx, s[tid][j]);
    float sum = 0.f;
    for (int j = 0; j < 49; ++j) { const float e = expf(s[tid][j] - mx); s[tid][j] = e; sum += e; }
    const float invs = 1.f / sum;
    for (int j = 0; j < 49; ++j) s[tid][j] *= invs;
  }
  __syncthreads();
  for (int id = tid; id < 49 * 24; id += 256) {
    const int i = id / 24, d = id - (id / 24) * 24;
    float acc = 0.f;
    #pragma unroll
    for (int j = 0; j < 49; ++j) acc = fmaf(s[i][j], vv[j][d], acc);
    outp[((size_t)(chunk * 12544) + wid * 49 + i) * C_DIM + h * 24 + d] = acc;
  }
}

// win-reverse + roll(+shift) + residual add into act
__global__ __launch_bounds__(256) void winrev_add_k(
    float* __restrict__ act, const float* __restrict__ pin, int shift)
{
  const int t = blockIdx.x * 4 + (threadIdx.x >> 6);
  const int lane = threadIdx.x & 63;
  const int win = t / 49, within = t - win * 49;
  const int b = win >> 6, wb = win & 63;
  int y = (wb >> 3) * 7 + within / 7 + shift; if (y >= IMG) y -= IMG;
  int x = (wb & 7) * 7 + within % 7 + shift; if (x >= IMG) x -= IMG;
  float* dst = act + ((size_t)b * HW_ + y * IMG + x) * C_DIM;
  const float* src = pin + (size_t)t * C_DIM;
  dst[lane]       += src[lane];
  dst[lane + 64]  += src[lane + 64];
  dst[lane + 128] += src[lane + 128];
}

// NHWC tokens -> NCHW (ds2 output)
__global__ __launch_bounds__(256) void transpose_k(
    const float* __restrict__ in, float* __restrict__ outp)
{
  __shared__ float tile[32][33];
  const int p0 = blockIdx.x * 32;
  const int c0 = blockIdx.y * 32;
  const int tid = threadIdx.x;
  #pragma unroll
  for (int it = 0; it < 4; ++it) {
    const int id = tid + it * 256;
    const int r = id >> 5, cc = id & 31;
    tile[r][cc] = in[(size_t)(p0 + r) * C_DIM + c0 + cc];
  }
  __syncthreads();
  const int b = p0 / HW_, pp0 = p0 - b * HW_;
  #pragma unroll
  for (int it = 0; it < 4; ++it) {
    const int id = tid + it * 256;
    const int cl = id >> 5, pl = id & 31;
    outp[((size_t)b * C_DIM + c0 + cl) * HW_ + pp0 + pl] = tile[pl][cl];
  }
}

// ---------------------------------------------------------------------------
extern "C" void kernel_launch(void* const* d_in, const int* in_sizes, int n_in,
                              void* d_out, int out_size, void* d_ws, size_t ws_size,
                              hipStream_t stream)
{
  const float* x       = (const float*)d_in[0];
  const float* pos     = (const float*)d_in[1];
  const float* proj_w  = (const float*)d_in[2];
  const float* proj_b  = (const float*)d_in[3];
  const float* pe_g    = (const float*)d_in[4];
  const float* pe_b    = (const float*)d_in[5];
  const float* n1_g    = (const float*)d_in[6];
  const float* n1_b    = (const float*)d_in[7];
  const float* qkv_w   = (const float*)d_in[8];
  const float* qkv_b   = (const float*)d_in[9];
  const float* attn_pw = (const float*)d_in[10];
  const float* attn_pb = (const float*)d_in[11];
  const float* rel_tab = (const float*)d_in[12];
  const float* n2_g    = (const float*)d_in[13];
  const float* n2_b    = (const float*)d_in[14];
  const float* fc1_w   = (const float*)d_in[15];
  const float* fc1_b   = (const float*)d_in[16];
  const float* fc2_w   = (const float*)d_in[17];
  const float* fc2_b   = (const float*)d_in[18];
  const float* c1_w    = (const float*)d_in[19];
  const float* c1_b    = (const float*)d_in[20];
  const float* bn1_g   = (const float*)d_in[21];
  const float* bn1_b   = (const float*)d_in[22];
  const float* bn1_m   = (const float*)d_in[23];
  const float* bn1_v   = (const float*)d_in[24];
  const float* c2_w    = (const float*)d_in[25];
  const float* c2_b    = (const float*)d_in[26];
  const float* bn2_g   = (const float*)d_in[27];
  const float* bn2_b   = (const float*)d_in[28];
  const float* bn2_m   = (const float*)d_in[29];
  const float* bn2_v   = (const float*)d_in[30];
  float* out = (float*)d_out;

  const size_t BUF = (size_t)NTOK * C_DIM * sizeof(float); // 38.5 MB
  char* ws = (char*)d_ws;
  float* act = (float*)ws;
  float* t1  = (float*)(ws + BUF);
  float* t2  = (float*)(ws + 2 * BUF);
  // t3 holds (qkv chunk | proj out) = up to 38.5 MB; fall back to d_out space
  // (57.8 MB, final contents written only at the very end) if ws is small.
  float* t3  = (ws_size >= 4 * BUF) ? (float*)(ws + 3 * BUF) : out;

  const dim3 blk(256);

  // Patch embed: 1x1 conv as GEMM (gathered A from NCHW), then LN + pos.
  gemm_k<AM_PATCH, EP_STORE, false><<<dim3(784, 3), blk, 0, stream>>>(
      x, proj_w, proj_b, t1, NTOK, 192, 192, nullptr, nullptr, nullptr, nullptr);
  ln_k<<<12544, blk, 0, stream>>>(t1, act, pe_g, pe_b, pos, 0, 0);

  for (int i = 0; i < 4; ++i) {
    const int shift = (i & 1) ? 3 : 0;
    // LN1 + roll + window partition
    ln_k<<<12544, blk, 0, stream>>>(act, t1, n1_g + i * 192, n1_b + i * 192,
                                    nullptr, 1, shift);
    // QKV + attention, in 4 chunks of 256 windows
    for (int c = 0; c < 4; ++c) {
      gemm_k<AM_PLAIN, EP_STORE, false><<<dim3(196, 9), blk, 0, stream>>>(
          t1 + (size_t)c * 12544 * 192, qkv_w + (size_t)i * 576 * 192,
          qkv_b + i * 576, t3, 12544, 576, 192, nullptr, nullptr, nullptr, nullptr);
      attn_k<<<2048, blk, 0, stream>>>(t3, t2, rel_tab + i * 169 * 8, shift, c);
    }
    // output projection over all windowed tokens
    gemm_k<AM_PLAIN, EP_STORE, false><<<dim3(784, 3), blk, 0, stream>>>(
        t2, attn_pw + (size_t)i * 192 * 192, attn_pb + i * 192, t3,
        NTOK, 192, 192, nullptr, nullptr, nullptr, nullptr);
    // window reverse + roll back + residual
    winrev_add_k<<<12544, blk, 0, stream>>>(act, t3, shift);
    // LN2 (plain order)
    ln_k<<<12544, blk, 0, stream>>>(act, t1, n2_g + i * 192, n2_b + i * 192,
                                    nullptr, 0, 0);
    // FFN in 4 token chunks: fc1+gelu -> hidden, fc2 -> += act
    for (int c = 0; c < 4; ++c) {
      gemm_k<AM_PLAIN, EP_GELU, false><<<dim3(196, 12), blk, 0, stream>>>(
          t1 + (size_t)c * 12544 * 192, fc1_w + (size_t)i * 768 * 192,
          fc1_b + i * 768, t2, 12544, 768, 192, nullptr, nullptr, nullptr, nullptr);
      gemm_k<AM_PLAIN, EP_ADD, false><<<dim3(196, 3), blk, 0, stream>>>(
          t2, fc2_w + (size_t)i * 192 * 768, fc2_b + i * 192,
          act + (size_t)c * 12544 * 192, 12544, 192, 768,
          nullptr, nullptr, nullptr, nullptr);
    }
  }

  // ds2 output (NHWC -> NCHW)
  transpose_k<<<dim3(1568, 6), blk, 0, stream>>>(act, out + CONV_OUT_SZ);
  // conv1 3x3 (implicit im2col GEMM, K=1728) + BN + ReLU -> NHWC tmp
  gemm_k<AM_CONV, EP_BN_NHWC, false><<<dim3(784, 3), blk, 0, stream>>>(
      act, c1_w, c1_b, t1, NTOK, 192, 1728, bn1_g, bn1_b, bn1_m, bn1_v);
  // conv2 3x3 + BN + ReLU -> NCHW d_out (N=96, needs n-guard)
  gemm_k<AM_CONV, EP_BN_NCHW, true><<<dim3(784, 2), blk, 0, stream>>>(
      t1, c2_w, c2_b, out, NTOK, 96, 1728, bn2_g, bn2_b, bn2_m, bn2_v);
}

// Round 3
// 1419.252 us; speedup vs baseline: 3.5524x; 3.5524x over previous
//
#include <hip/hip_runtime.h>
#include <math.h>

typedef unsigned short u16;
typedef unsigned int u32;
typedef __attribute__((ext_vector_type(8))) short short8;
typedef __attribute__((ext_vector_type(4))) float f32x4;

#define IMG 56
#define HW_ 3136
#define NTOK 50176
#define C_DIM 192
#define CONV_OUT_SZ 4816896  /* 16*96*3136 floats */

__device__ inline float bf2f(u16 v) {
  u32 u = ((u32)v) << 16; float f; __builtin_memcpy(&f, &u, 4); return f;
}
__device__ inline u16 f2bf(float f) {
  u32 u; __builtin_memcpy(&u, &f, 4);
  u += 0x7FFF + ((u >> 16) & 1);
  return (u16)(u >> 16);
}
__device__ inline void glds16(const u16* g, u16* l) {
  __builtin_amdgcn_global_load_lds((const __attribute__((address_space(1))) u32*)g,
                                   (__attribute__((address_space(3))) u32*)l, 16, 0, 0);
}

// ---------------------------------------------------------------------------
// MFMA bf16 GEMM: C[m,n] = epi( sum_k A[m,k]*W[n,k] + bias[n] )
// BM=128, BN=64, BK=64, 256 threads (4 waves, 2x2), 16x16x32 MFMA.
// LDS XOR-swizzle (byte ^= (row&7)<<4); A/B staged via global_load_lds with
// pre-swizzled global source (both-sides-or-neither). AMODE 1 = implicit
// im2col 3x3 conv gather (reg-staged, swizzled ds_write).
// EPI: 0 store bf16, 1 gelu->bf16, 2 +=f32, 3 BN+relu->bf16 NHWC,
//      4 BN+relu->f32 NCHW (guard c<N), 5 store f32.
// ---------------------------------------------------------------------------
template<int AMODE, int EPI>
__global__ __launch_bounds__(256) void gmm(
    const u16* __restrict__ A, const u16* __restrict__ W,
    const float* __restrict__ bias, void* __restrict__ Cout,
    int M, int N, int K,
    const float* __restrict__ bg, const float* __restrict__ bb,
    const float* __restrict__ bm, const float* __restrict__ bv)
{
  __shared__ u16 As[128 * 64];
  __shared__ u16 Bs[64 * 64];
  const int tid = threadIdx.x;
  const int m0 = blockIdx.x * 128, n0 = blockIdx.y * 64;
  const int lane = tid & 63, wid = tid >> 6;
  const int wm = (wid >> 1) * 64, wn = (wid & 1) * 32;
  const int fr = lane & 15, fg = lane >> 4;
  f32x4 acc[4][2] = {};

  for (int kc = 0; kc < K; kc += 64) {
    // ---- stage B (64 n-rows x 64 k) : 2 x 16B per thread
    #pragma unroll
    for (int it = 0; it < 2; ++it) {
      const int g = it * 256 + tid;
      const int row = g >> 3, cb = (g & 7) << 4;
      const int sc = cb ^ ((row & 7) << 4);
      glds16(W + (size_t)(n0 + row) * K + kc + (sc >> 1), Bs + g * 8);
    }
    // ---- stage A (128 m-rows x 64 k) : 4 x 16B per thread
    if (AMODE == 0) {
      #pragma unroll
      for (int it = 0; it < 4; ++it) {
        const int g = it * 256 + tid;
        const int row = g >> 3, cb = (g & 7) << 4;
        const int sc = cb ^ ((row & 7) << 4);
        glds16(A + (size_t)(m0 + row) * K + kc + (sc >> 1), As + g * 8);
      }
    } else {
      #pragma unroll
      for (int it = 0; it < 4; ++it) {
        const int g = it * 256 + tid;
        const int row = g >> 3, cb = (g & 7) << 4;
        const int m = m0 + row;
        const int b = m / HW_, pp = m - b * HW_;
        const int y = pp / IMG, x = pp - (pp / IMG) * IMG;
        const int kg = kc + (cb >> 1);
        const int s = kg / C_DIM, ic = kg - s * C_DIM;
        const int yy = y + s / 3 - 1, xx = x + (s % 3) - 1;
        short8 v = {0, 0, 0, 0, 0, 0, 0, 0};
        if ((unsigned)yy < IMG && (unsigned)xx < IMG)
          v = *(const short8*)(A + ((size_t)(b * HW_ + yy * IMG + xx)) * C_DIM + ic);
        *(short8*)(As + row * 64 + ((cb ^ ((row & 7) << 4)) >> 1)) = v;
      }
    }
    __syncthreads();
    #pragma unroll
    for (int ks = 0; ks < 2; ++ks) {
      const int kb = ks * 64 + fg * 16;  // byte col within 128B row
      short8 af[4], bf[2];
      #pragma unroll
      for (int i = 0; i < 4; ++i) {
        const int row = wm + i * 16 + fr;
        af[i] = *(const short8*)(As + ((row * 128 + (kb ^ ((row & 7) << 4))) >> 1));
      }
      #pragma unroll
      for (int j = 0; j < 2; ++j) {
        const int row = wn + j * 16 + fr;
        bf[j] = *(const short8*)(Bs + ((row * 128 + (kb ^ ((row & 7) << 4))) >> 1));
      }
      #pragma unroll
      for (int i = 0; i < 4; ++i)
        #pragma unroll
        for (int j = 0; j < 2; ++j)
          acc[i][j] = __builtin_amdgcn_mfma_f32_16x16x32_bf16(af[i], bf[j], acc[i][j], 0, 0, 0);
    }
    __syncthreads();
  }

  // ---- epilogue. C/D: col = lane&15, row = fg*4 + reg.
  const int c0 = n0 + wn + fr;
  const int c1i = (EPI == 4) ? min(c0 + 16, N - 1) : (c0 + 16);
  const float bias0 = bias[c0], bias1 = bias[c1i];
  float s0 = 0.f, h0 = 0.f, s1 = 0.f, h1 = 0.f;
  if (EPI == 3 || EPI == 4) {
    s0 = bg[c0] * rsqrtf(bv[c0] + 1e-5f); h0 = bb[c0] - bm[c0] * s0;
    s1 = bg[c1i] * rsqrtf(bv[c1i] + 1e-5f); h1 = bb[c1i] - bm[c1i] * s1;
  }
  #pragma unroll
  for (int i = 0; i < 4; ++i) {
    #pragma unroll
    for (int r = 0; r < 4; ++r) {
      const int m = m0 + wm + i * 16 + fg * 4 + r;
      #pragma unroll
      for (int j = 0; j < 2; ++j) {
        const int c = c0 + j * 16;
        float v = acc[i][j][r] + (j ? bias1 : bias0);
        if (EPI == 1) v = 0.5f * v * (1.f + erff(v * 0.70710678118f));
        if (EPI == 3 || EPI == 4) { v = v * (j ? s1 : s0) + (j ? h1 : h0); v = fmaxf(v, 0.f); }
        if (EPI == 0 || EPI == 1 || EPI == 3) {
          ((u16*)Cout)[(size_t)m * N + c] = f2bf(v);
        } else if (EPI == 5) {
          ((float*)Cout)[(size_t)m * N + c] = v;
        } else if (EPI == 2) {
          ((float*)Cout)[(size_t)m * N + c] += v;
        } else {  // EPI 4: NCHW f32, guard
          if (c < N) {
            const int b = m / HW_, pp = m - b * HW_;
            ((float*)Cout)[((size_t)b * N + c) * HW_ + pp] = v;
          }
        }
      }
    }
  }
}

// ---------------------------------------------------------------------------
__device__ inline void stv(float* p, float v) { *p = v; }
__device__ inline void stv(u16* p, float v) { *p = f2bf(v); }

// LayerNorm over C=192, wave-per-token. winpart: roll(-shift)+window scatter.
template<typename OT>
__global__ __launch_bounds__(256) void ln_k(
    const float* __restrict__ in, OT* __restrict__ outp,
    const float* __restrict__ g, const float* __restrict__ bta,
    const float* __restrict__ pos, int winpart, int shift)
{
  const int t = blockIdx.x * 4 + (threadIdx.x >> 6);
  const int lane = threadIdx.x & 63;
  const float* xr = in + (size_t)t * C_DIM;
  const float v0 = xr[lane], v1 = xr[lane + 64], v2 = xr[lane + 128];
  float s = v0 + v1 + v2;
  float ss = v0 * v0 + v1 * v1 + v2 * v2;
  #pragma unroll
  for (int off = 32; off > 0; off >>= 1) {
    s += __shfl_xor(s, off);
    ss += __shfl_xor(ss, off);
  }
  const float mean = s * (1.f / 192.f);
  const float inv = rsqrtf(ss * (1.f / 192.f) - mean * mean + 1e-5f);
  const int b = t / HW_, pp = t - b * HW_;
  size_t obase;
  if (winpart) {
    const int y = pp / IMG, x = pp - (pp / IMG) * IMG;
    int yr = y - shift; if (yr < 0) yr += IMG;
    int xs = x - shift; if (xs < 0) xs += IMG;
    const int win = b * 64 + (yr / 7) * 8 + (xs / 7);
    const int within = (yr % 7) * 7 + (xs % 7);
    obase = ((size_t)win * 49 + within) * C_DIM;
  } else {
    obase = (size_t)t * C_DIM;
  }
  OT* o = outp + obase;
  float p0 = 0.f, p1 = 0.f, p2 = 0.f;
  if (pos) {
    const float* pr = pos + (size_t)pp * C_DIM;
    p0 = pr[lane]; p1 = pr[lane + 64]; p2 = pr[lane + 128];
  }
  stv(o + lane,       (v0 - mean) * inv * g[lane]       + bta[lane]       + p0);
  stv(o + lane + 64,  (v1 - mean) * inv * g[lane + 64]  + bta[lane + 64]  + p1);
  stv(o + lane + 128, (v2 - mean) * inv * g[lane + 128] + bta[lane + 128] + p2);
}

// ---------------------------------------------------------------------------
// Window attention (fp32 math, bf16 I/O). One block per (window, head).
__global__ __launch_bounds__(256) void attn_k(
    const u16* __restrict__ qkv, u16* __restrict__ outp,
    const float* __restrict__ rel, int shift)
{
  __shared__ float q[49][25], kk[49][25], vv[49][25];
  __shared__ float s[49][50];
  const int h = blockIdx.x & 7;
  const int win = blockIdx.x >> 3;
  const int tid = threadIdx.x;
  const u16* base = qkv + (size_t)win * 49 * 576 + h * 24;
  for (int id = tid; id < 49 * 24; id += 256) {
    const int i = id / 24, d = id - (id / 24) * 24;
    q[i][d]  = bf2f(base[i * 576 + d]) * 0.20412414523193154f;
    kk[i][d] = bf2f(base[i * 576 + 192 + d]);
    vv[i][d] = bf2f(base[i * 576 + 384 + d]);
  }
  __syncthreads();
  const int wb = win & 63;
  const int hblk = wb >> 3, wblk = wb & 7;
  for (int id = tid; id < 49 * 49; id += 256) {
    const int i = id / 49, j = id - (id / 49) * 49;
    float acc = 0.f;
    #pragma unroll
    for (int d = 0; d < 24; ++d) acc = fmaf(q[i][d], kk[j][d], acc);
    const int r1 = i / 7, c1 = i - r1 * 7, r2 = j / 7, c2 = j - r2 * 7;
    acc += rel[((r1 - r2 + 6) * 13 + (c1 - c2 + 6)) * 8 + h];
    if (shift) {
      const int hi = hblk * 7 + r1, wi = wblk * 7 + c1;
      const int hj = hblk * 7 + r2, wj = wblk * 7 + c2;
      const int ri = (hi < 49 ? 0 : (hi < 53 ? 1 : 2)) * 3 + (wi < 49 ? 0 : (wi < 53 ? 1 : 2));
      const int rj = (hj < 49 ? 0 : (hj < 53 ? 1 : 2)) * 3 + (wj < 49 ? 0 : (wj < 53 ? 1 : 2));
      if (ri != rj) acc -= 100.f;
    }
    s[i][j] = acc;
  }
  __syncthreads();
  if (tid < 49) {
    float mx = -1e30f;
    for (int j = 0; j < 49; ++j) mx = fmaxf(mx, s[tid][j]);
    float sum = 0.f;
    for (int j = 0; j < 49; ++j) { const float e = expf(s[tid][j] - mx); s[tid][j] = e; sum += e; }
    const float invs = 1.f / sum;
    for (int j = 0; j < 49; ++j) s[tid][j] *= invs;
  }
  __syncthreads();
  for (int id = tid; id < 49 * 24; id += 256) {
    const int i = id / 24, d = id - (id / 24) * 24;
    float acc = 0.f;
    #pragma unroll
    for (int j = 0; j < 49; ++j) acc = fmaf(s[i][j], vv[j][d], acc);
    outp[((size_t)win * 49 + i) * C_DIM + h * 24 + d] = f2bf(acc);
  }
}

// win-reverse + roll(+shift) + residual add (bf16 src) into f32 act
__global__ __launch_bounds__(256) void winrev_add_k(
    float* __restrict__ act, const u16* __restrict__ pin, int shift)
{
  const int t = blockIdx.x * 4 + (threadIdx.x >> 6);
  const int lane = threadIdx.x & 63;
  const int win = t / 49, within = t - win * 49;
  const int b = win >> 6, wb = win & 63;
  int y = (wb >> 3) * 7 + within / 7 + shift; if (y >= IMG) y -= IMG;
  int x = (wb & 7) * 7 + within % 7 + shift; if (x >= IMG) x -= IMG;
  float* dst = act + ((size_t)b * HW_ + y * IMG + x) * C_DIM;
  const u16* src = pin + (size_t)t * C_DIM;
  dst[lane]       += bf2f(src[lane]);
  dst[lane + 64]  += bf2f(src[lane + 64]);
  dst[lane + 128] += bf2f(src[lane + 128]);
}

// NHWC f32 tokens -> NCHW f32 (ds2 output)
__global__ __launch_bounds__(256) void transpose_k(
    const float* __restrict__ in, float* __restrict__ outp)
{
  __shared__ float tile[32][33];
  const int p0 = blockIdx.x * 32;
  const int c0 = blockIdx.y * 32;
  const int tid = threadIdx.x;
  #pragma unroll
  for (int it = 0; it < 4; ++it) {
    const int id = tid + it * 256;
    const int r = id >> 5, cc = id & 31;
    tile[r][cc] = in[(size_t)(p0 + r) * C_DIM + c0 + cc];
  }
  __syncthreads();
  const int b = p0 / HW_, pp0 = p0 - b * HW_;
  #pragma unroll
  for (int it = 0; it < 4; ++it) {
    const int id = tid + it * 256;
    const int cl = id >> 5, pl = id & 31;
    outp[((size_t)b * C_DIM + c0 + cl) * HW_ + pp0 + pl] = tile[pl][cl];
  }
}

// NCHW f32 -> token-major bf16
__global__ __launch_bounds__(256) void tok_k(
    const float* __restrict__ in, u16* __restrict__ outp)
{
  __shared__ float tile[32][33];
  const int t0 = blockIdx.x * 32;
  const int c0 = blockIdx.y * 32;
  const int tid = threadIdx.x;
  const int b = t0 / HW_, p0 = t0 - b * HW_;
  #pragma unroll
  for (int it = 0; it < 4; ++it) {
    const int id = tid + it * 256;
    const int cl = id >> 5, pl = id & 31;
    tile[cl][pl] = in[((size_t)b * C_DIM + c0 + cl) * HW_ + p0 + pl];
  }
  __syncthreads();
  #pragma unroll
  for (int it = 0; it < 4; ++it) {
    const int id = tid + it * 256;
    const int r = id >> 5, cc = id & 31;
    outp[(size_t)(t0 + r) * C_DIM + c0 + cc] = f2bf(tile[cc][r]);
  }
}

// flat f32 -> bf16 (vectorized x4)
__global__ __launch_bounds__(256) void cvt_k(
    const float* __restrict__ in, u16* __restrict__ outp, int n4)
{
  const int i = blockIdx.x * 256 + threadIdx.x;
  if (i >= n4) return;
  const float4 v = ((const float4*)in)[i];
  u32 lo = (u32)f2bf(v.x) | ((u32)f2bf(v.y) << 16);
  u32 hi = (u32)f2bf(v.z) | ((u32)f2bf(v.w) << 16);
  ((uint2*)outp)[i] = make_uint2(lo, hi);
}

// conv weight (OC,IC,3,3) f32 -> [OCpad][9*192] bf16 (im2col row-major)
__global__ __launch_bounds__(256) void cvtconv_k(
    const float* __restrict__ src, u16* __restrict__ dst, int OC, int OCpad)
{
  const int idx = blockIdx.x * 256 + threadIdx.x;
  if (idx >= OCpad * 1728) return;
  const int n = idx / 1728, kkk = idx - n * 1728;
  const int s = kkk / C_DIM, ic = kkk - s * C_DIM;
  dst[idx] = (n < OC) ? f2bf(src[((size_t)n * C_DIM + ic) * 9 + s]) : (u16)0;
}

// ---------------------------------------------------------------------------
extern "C" void kernel_launch(void* const* d_in, const int* in_sizes, int n_in,
                              void* d_out, int out_size, void* d_ws, size_t ws_size,
                              hipStream_t stream)
{
  const float* x       = (const float*)d_in[0];
  const float* pos     = (const float*)d_in[1];
  const float* proj_w  = (const float*)d_in[2];
  const float* proj_b  = (const float*)d_in[3];
  const float* pe_g    = (const float*)d_in[4];
  const float* pe_b    = (const float*)d_in[5];
  const float* n1_g    = (const float*)d_in[6];
  const float* n1_b    = (const float*)d_in[7];
  const float* qkv_w   = (const float*)d_in[8];
  const float* qkv_b   = (const float*)d_in[9];
  const float* attn_pw = (const float*)d_in[10];
  const float* attn_pb = (const float*)d_in[11];
  const float* rel_tab = (const float*)d_in[12];
  const float* n2_g    = (const float*)d_in[13];
  const float* n2_b    = (const float*)d_in[14];
  const float* fc1_w   = (const float*)d_in[15];
  const float* fc1_b   = (const float*)d_in[16];
  const float* fc2_w   = (const float*)d_in[17];
  const float* fc2_b   = (const float*)d_in[18];
  const float* c1_w    = (const float*)d_in[19];
  const float* c1_b    = (const float*)d_in[20];
  const float* bn1_g   = (const float*)d_in[21];
  const float* bn1_b   = (const float*)d_in[22];
  const float* bn1_m   = (const float*)d_in[23];
  const float* bn1_v   = (const float*)d_in[24];
  const float* c2_w    = (const float*)d_in[25];
  const float* c2_b    = (const float*)d_in[26];
  const float* bn2_g   = (const float*)d_in[27];
  const float* bn2_b   = (const float*)d_in[28];
  const float* bn2_m   = (const float*)d_in[29];
  const float* bn2_v   = (const float*)d_in[30];
  float* out = (float*)d_out;

  // ws layout (exactly 3*BUF = 115.6MB, same footprint as the passing round):
  const size_t BUF  = (size_t)NTOK * C_DIM * 4;   // 38,535,168 B
  const size_t BIGB = (size_t)NTOK * 576 * 2;     // 57,802,752 B
  char* ws = (char*)d_ws;
  float* act   = (float*)ws;                       // f32 residual stream
  u16*   big16 = (u16*)(ws + BUF);                 // qkv / hidden-chunk / conv1_out
  float* big32 = (float*)(ws + BUF);               // patch-gemm f32 out
  u16*   xln   = (u16*)(ws + BUF + BIGB);          // x_tok / LN out / proj out / act_bf
  // d_out scratch: attn_out in [0,19.3MB), bf16 weights in ds2 region
  // (overwritten by conv2 / final transpose, which run last).
  u16* attn_out = (u16*)d_out;
  u16* wbf = (u16*)((char*)d_out + (size_t)CONV_OUT_SZ * 4);

  const size_t O_QKV = 0;
  const size_t O_FC1 = O_QKV + (size_t)4 * 576 * 192;
  const size_t O_FC2 = O_FC1 + (size_t)4 * 768 * 192;
  const size_t O_PW  = O_FC2 + (size_t)4 * 192 * 768;
  const size_t O_PROJ= O_PW  + (size_t)4 * 192 * 192;
  const size_t O_C1  = O_PROJ+ (size_t)192 * 192;
  const size_t O_C2  = O_C1  + (size_t)192 * 1728;

  const dim3 blk(256);

  // ---- weight conversion (bf16, im2col layout for convs; c2 padded to 128)
  cvt_k<<<(4*576*192/4 + 255)/256, blk, 0, stream>>>(qkv_w,   wbf + O_QKV, 4*576*192/4);
  cvt_k<<<(4*768*192/4 + 255)/256, blk, 0, stream>>>(fc1_w,   wbf + O_FC1, 4*768*192/4);
  cvt_k<<<(4*192*768/4 + 255)/256, blk, 0, stream>>>(fc2_w,   wbf + O_FC2, 4*192*768/4);
  cvt_k<<<(4*192*192/4 + 255)/256, blk, 0, stream>>>(attn_pw, wbf + O_PW,  4*192*192/4);
  cvt_k<<<(192*192/4   + 255)/256, blk, 0, stream>>>(proj_w,  wbf + O_PROJ, 192*192/4);
  cvtconv_k<<<(192*1728 + 255)/256, blk, 0, stream>>>(c1_w, wbf + O_C1, 192, 192);
  cvtconv_k<<<(128*1728 + 255)/256, blk, 0, stream>>>(c2_w, wbf + O_C2, 96, 128);

  // ---- patch embed: x NCHW -> bf16 tokens -> GEMM -> LN(+pos) -> act f32
  tok_k<<<dim3(1568, 6), blk, 0, stream>>>(x, xln);
  gmm<0, 5><<<dim3(392, 3), blk, 0, stream>>>(
      xln, wbf + O_PROJ, proj_b, big32, NTOK, 192, 192, nullptr, nullptr, nullptr, nullptr);
  ln_k<float><<<12544, blk, 0, stream>>>(big32, act, pe_g, pe_b, pos, 0, 0);

  for (int i = 0; i < 4; ++i) {
    const int shift = (i & 1) ? 3 : 0;
    ln_k<u16><<<12544, blk, 0, stream>>>(act, xln, n1_g + i * 192, n1_b + i * 192,
                                         nullptr, 1, shift);
    gmm<0, 0><<<dim3(392, 9), blk, 0, stream>>>(
        xln, wbf + O_QKV + (size_t)i * 576 * 192, qkv_b + i * 576, big16,
        NTOK, 576, 192, nullptr, nullptr, nullptr, nullptr);
    attn_k<<<8192, blk, 0, stream>>>(big16, attn_out, rel_tab + i * 169 * 8, shift);
    gmm<0, 0><<<dim3(392, 3), blk, 0, stream>>>(
        attn_out, wbf + O_PW + (size_t)i * 192 * 192, attn_pb + i * 192, xln,
        NTOK, 192, 192, nullptr, nullptr, nullptr, nullptr);
    winrev_add_k<<<12544, blk, 0, stream>>>(act, xln, shift);
    ln_k<u16><<<12544, blk, 0, stream>>>(act, xln, n2_g + i * 192, n2_b + i * 192,
                                         nullptr, 0, 0);
    for (int c = 0; c < 2; ++c) {
      gmm<0, 1><<<dim3(196, 12), blk, 0, stream>>>(
          xln + (size_t)c * 25088 * 192, wbf + O_FC1 + (size_t)i * 768 * 192,
          fc1_b + i * 768, big16, 25088, 768, 192, nullptr, nullptr, nullptr, nullptr);
      gmm<0, 2><<<dim3(196, 3), blk, 0, stream>>>(
          big16, wbf + O_FC2 + (size_t)i * 192 * 768, fc2_b + i * 192,
          act + (size_t)c * 25088 * 192, 25088, 192, 768, nullptr, nullptr, nullptr, nullptr);
    }
  }

  // ---- conv head: act -> bf16 NHWC, conv1 (BN+relu, bf16 NHWC), conv2 (BN+relu, NCHW f32)
  cvt_k<<<(NTOK * C_DIM / 4 + 255)/256, blk, 0, stream>>>(act, xln, NTOK * C_DIM / 4);
  gmm<1, 3><<<dim3(392, 3), blk, 0, stream>>>(
      xln, wbf + O_C1, c1_b, big16, NTOK, 192, 1728, bn1_g, bn1_b, bn1_m, bn1_v);
  gmm<1, 4><<<dim3(392, 2), blk, 0, stream>>>(
      big16, wbf + O_C2, c2_b, out, NTOK, 96, 1728, bn2_g, bn2_b, bn2_m, bn2_v);
  // ds2 output last (it overwrites the wbf scratch region in d_out)
  transpose_k<<<dim3(1568, 6), blk, 0, stream>>>(act, out + CONV_OUT_SZ);
}

// Round 5
// 1101.531 us; speedup vs baseline: 4.5770x; 1.2884x over previous
//
#include <hip/hip_runtime.h>
#include <math.h>

typedef unsigned short u16;
typedef unsigned int u32;
typedef __attribute__((ext_vector_type(8))) short short8;
typedef __attribute__((ext_vector_type(4))) float f32x4;

#define IMG 56
#define HW_ 3136
#define NTOK 50176
#define C_DIM 192
#define CONV_OUT_SZ 4816896  /* 16*96*3136 floats */

__device__ inline float bf2f(u16 v) {
  u32 u = ((u32)v) << 16; float f; __builtin_memcpy(&f, &u, 4); return f;
}
__device__ inline u16 f2bf(float f) {
  u32 u; __builtin_memcpy(&u, &f, 4);
  u += 0x7FFF + ((u >> 16) & 1);
  return (u16)(u >> 16);
}
__device__ inline void glds16(const u16* g, u16* l) {
  __builtin_amdgcn_global_load_lds((const __attribute__((address_space(1))) u32*)g,
                                   (__attribute__((address_space(3))) u32*)l, 16, 0, 0);
}

// ---------------------------------------------------------------------------
// MFMA bf16 GEMM: C[m,n] = epi( sum_k A[m,k]*W[n,k] + bias[n] )
// BM=128, BN=64, BK=64, 256 threads (4 waves, 2x2), 16x16x32 MFMA.
// ---------------------------------------------------------------------------
template<int AMODE, int EPI>
__global__ __launch_bounds__(256) void gmm(
    const u16* __restrict__ A, const u16* __restrict__ W,
    const float* __restrict__ bias, void* __restrict__ Cout,
    int M, int N, int K,
    const float* __restrict__ bg, const float* __restrict__ bb,
    const float* __restrict__ bm, const float* __restrict__ bv)
{
  __shared__ u16 As[128 * 64];
  __shared__ u16 Bs[64 * 64];
  const int tid = threadIdx.x;
  const int m0 = blockIdx.x * 128, n0 = blockIdx.y * 64;
  const int lane = tid & 63, wid = tid >> 6;
  const int wm = (wid >> 1) * 64, wn = (wid & 1) * 32;
  const int fr = lane & 15, fg = lane >> 4;
  f32x4 acc[4][2] = {};

  for (int kc = 0; kc < K; kc += 64) {
    #pragma unroll
    for (int it = 0; it < 2; ++it) {
      const int g = it * 256 + tid;
      const int row = g >> 3, cb = (g & 7) << 4;
      const int sc = cb ^ ((row & 7) << 4);
      glds16(W + (size_t)(n0 + row) * K + kc + (sc >> 1), Bs + g * 8);
    }
    if (AMODE == 0) {
      #pragma unroll
      for (int it = 0; it < 4; ++it) {
        const int g = it * 256 + tid;
        const int row = g >> 3, cb = (g & 7) << 4;
        const int sc = cb ^ ((row & 7) << 4);
        glds16(A + (size_t)(m0 + row) * K + kc + (sc >> 1), As + g * 8);
      }
    } else {
      #pragma unroll
      for (int it = 0; it < 4; ++it) {
        const int g = it * 256 + tid;
        const int row = g >> 3, cb = (g & 7) << 4;
        const int m = m0 + row;
        const int b = m / HW_, pp = m - b * HW_;
        const int y = pp / IMG, x = pp - (pp / IMG) * IMG;
        const int kg = kc + (cb >> 1);
        const int s = kg / C_DIM, ic = kg - s * C_DIM;
        const int yy = y + s / 3 - 1, xx = x + (s % 3) - 1;
        short8 v = {0, 0, 0, 0, 0, 0, 0, 0};
        if ((unsigned)yy < IMG && (unsigned)xx < IMG)
          v = *(const short8*)(A + ((size_t)(b * HW_ + yy * IMG + xx)) * C_DIM + ic);
        *(short8*)(As + row * 64 + ((cb ^ ((row & 7) << 4)) >> 1)) = v;
      }
    }
    __syncthreads();
    #pragma unroll
    for (int ks = 0; ks < 2; ++ks) {
      const int kb = ks * 64 + fg * 16;
      short8 af[4], bf[2];
      #pragma unroll
      for (int i = 0; i < 4; ++i) {
        const int row = wm + i * 16 + fr;
        af[i] = *(const short8*)(As + ((row * 128 + (kb ^ ((row & 7) << 4))) >> 1));
      }
      #pragma unroll
      for (int j = 0; j < 2; ++j) {
        const int row = wn + j * 16 + fr;
        bf[j] = *(const short8*)(Bs + ((row * 128 + (kb ^ ((row & 7) << 4))) >> 1));
      }
      #pragma unroll
      for (int i = 0; i < 4; ++i)
        #pragma unroll
        for (int j = 0; j < 2; ++j)
          acc[i][j] = __builtin_amdgcn_mfma_f32_16x16x32_bf16(af[i], bf[j], acc[i][j], 0, 0, 0);
    }
    __syncthreads();
  }

  const int c0 = n0 + wn + fr;
  const int c1i = (EPI == 4) ? min(c0 + 16, N - 1) : (c0 + 16);
  const float bias0 = bias[c0], bias1 = bias[c1i];
  float s0 = 0.f, h0 = 0.f, s1 = 0.f, h1 = 0.f;
  if (EPI == 3 || EPI == 4) {
    s0 = bg[c0] * rsqrtf(bv[c0] + 1e-5f); h0 = bb[c0] - bm[c0] * s0;
    s1 = bg[c1i] * rsqrtf(bv[c1i] + 1e-5f); h1 = bb[c1i] - bm[c1i] * s1;
  }
  #pragma unroll
  for (int i = 0; i < 4; ++i) {
    #pragma unroll
    for (int r = 0; r < 4; ++r) {
      const int m = m0 + wm + i * 16 + fg * 4 + r;
      #pragma unroll
      for (int j = 0; j < 2; ++j) {
        const int c = c0 + j * 16;
        float v = acc[i][j][r] + (j ? bias1 : bias0);
        if (EPI == 1) v = 0.5f * v * (1.f + erff(v * 0.70710678118f));
        if (EPI == 3 || EPI == 4) { v = v * (j ? s1 : s0) + (j ? h1 : h0); v = fmaxf(v, 0.f); }
        if (EPI == 0 || EPI == 1 || EPI == 3) {
          ((u16*)Cout)[(size_t)m * N + c] = f2bf(v);
        } else if (EPI == 5) {
          ((float*)Cout)[(size_t)m * N + c] = v;
        } else if (EPI == 2) {
          ((float*)Cout)[(size_t)m * N + c] += v;
        } else {
          if (c < N) {
            const int b = m / HW_, pp = m - b * HW_;
            ((float*)Cout)[((size_t)b * N + c) * HW_ + pp] = v;
          }
        }
      }
    }
  }
}

// ---------------------------------------------------------------------------
__device__ inline void stv(float* p, float v) { *p = v; }
__device__ inline void stv(u16* p, float v) { *p = f2bf(v); }

template<typename OT>
__global__ __launch_bounds__(256) void ln_k(
    const float* __restrict__ in, OT* __restrict__ outp,
    const float* __restrict__ g, const float* __restrict__ bta,
    const float* __restrict__ pos, int winpart, int shift)
{
  const int t = blockIdx.x * 4 + (threadIdx.x >> 6);
  const int lane = threadIdx.x & 63;
  const float* xr = in + (size_t)t * C_DIM;
  const float v0 = xr[lane], v1 = xr[lane + 64], v2 = xr[lane + 128];
  float s = v0 + v1 + v2;
  float ss = v0 * v0 + v1 * v1 + v2 * v2;
  #pragma unroll
  for (int off = 32; off > 0; off >>= 1) {
    s += __shfl_xor(s, off);
    ss += __shfl_xor(ss, off);
  }
  const float mean = s * (1.f / 192.f);
  const float inv = rsqrtf(ss * (1.f / 192.f) - mean * mean + 1e-5f);
  const int b = t / HW_, pp = t - b * HW_;
  size_t obase;
  if (winpart) {
    const int y = pp / IMG, x = pp - (pp / IMG) * IMG;
    int yr = y - shift; if (yr < 0) yr += IMG;
    int xs = x - shift; if (xs < 0) xs += IMG;
    const int win = b * 64 + (yr / 7) * 8 + (xs / 7);
    const int within = (yr % 7) * 7 + (xs % 7);
    obase = ((size_t)win * 49 + within) * C_DIM;
  } else {
    obase = (size_t)t * C_DIM;
  }
  OT* o = outp + obase;
  float p0 = 0.f, p1 = 0.f, p2 = 0.f;
  if (pos) {
    const float* pr = pos + (size_t)pp * C_DIM;
    p0 = pr[lane]; p1 = pr[lane + 64]; p2 = pr[lane + 128];
  }
  stv(o + lane,       (v0 - mean) * inv * g[lane]       + bta[lane]       + p0);
  stv(o + lane + 64,  (v1 - mean) * inv * g[lane + 64]  + bta[lane + 64]  + p1);
  stv(o + lane + 128, (v2 - mean) * inv * g[lane + 128] + bta[lane + 128] + p2);
}

// ---------------------------------------------------------------------------
// MFMA window attention. Block = 4 waves; wave = one (window, head).
// win = blockIdx.x>>1, heads (blockIdx.x&1)*4 + waveid.
// Q/K fragments direct from global; V^T and P staged in swizzled LDS.
// ---------------------------------------------------------------------------
__global__ __launch_bounds__(256) void attn_m(
    const u16* __restrict__ qkv, u16* __restrict__ outp,
    const float* __restrict__ rel, int shift)
{
  __shared__ u16 VT[128 * 64];       // [d' = wave*32 + dl][j], swizzle key (row>>2)&7
  __shared__ u16 Pbuf[4][64 * 64];   // per-wave P[i][j], swizzle key row&7
  const int tid = threadIdx.x;
  const int wid = tid >> 6, lane = tid & 63;
  const int fr = lane & 15, fg = lane >> 4;
  const int win = blockIdx.x >> 1;
  const int hb = blockIdx.x & 1;
  const int h = hb * 4 + wid;
  const u16* wbase = qkv + (size_t)win * 49 * 576;

  // zero-fill VT (covers j>=49 and dl>=24 padding)
  {
    u32* vz = (u32*)VT;
    #pragma unroll
    for (int it = 0; it < 16; ++it) vz[it * 256 + tid] = 0;
  }
  __syncthreads();
  // stage V^T for this block's 4 heads (global d = hb*96 + dd)
  for (int id = tid; id < 49 * 24; id += 256) {
    const int j = id / 24, dq = id - (id / 24) * 24;
    const int dd = dq * 4;
    const uint2 v = *(const uint2*)(wbase + j * 576 + 384 + hb * 96 + dd);
    const u16* pv = (const u16*)&v;
    const int wpr = dd / 24, dl = dd - wpr * 24;
    #pragma unroll
    for (int e = 0; e < 4; ++e) {
      const int row = wpr * 32 + dl + e;
      VT[(row * 128 + ((j * 2) ^ (((row >> 2) & 7) << 4))) >> 1] = pv[e];
    }
  }
  __syncthreads();

  // Q/K fragments: lane(fr,fg) holds rows t*16+fr, d = fg*8..+7 (fg==3 zero pad)
  short8 qf[4], kf[4];
  #pragma unroll
  for (int t = 0; t < 4; ++t) {
    const int row = t * 16 + fr;
    if (fg < 3) {
      qf[t] = *(const short8*)(wbase + row * 576 + h * 24 + fg * 8);
      kf[t] = *(const short8*)(wbase + row * 576 + 192 + h * 24 + fg * 8);
    } else {
      qf[t] = (short8){0, 0, 0, 0, 0, 0, 0, 0};
      kf[t] = (short8){0, 0, 0, 0, 0, 0, 0, 0};
    }
  }

  const int wb = win & 63;
  const int hblk = wb >> 3, wblk = wb & 7;
  u16* Pw = Pbuf[wid];

  #pragma unroll
  for (int mi = 0; mi < 4; ++mi) {
    f32x4 s_acc[4];
    #pragma unroll
    for (int nj = 0; nj < 4; ++nj)
      s_acc[nj] = __builtin_amdgcn_mfma_f32_16x16x32_bf16(qf[mi], kf[nj],
                                                          (f32x4){0, 0, 0, 0}, 0, 0, 0);
    // softmax over j for rows i = mi*16 + fg*4 + rr
    #pragma unroll
    for (int rr = 0; rr < 4; ++rr) {
      const int i = mi * 16 + fg * 4 + rr;
      const int r1 = i / 7, c1 = i - r1 * 7;
      int ri = 0;
      if (shift) {
        const int hi = hblk * 7 + r1, wi2 = wblk * 7 + c1;
        ri = (hi < 49 ? 0 : (hi < 53 ? 1 : 2)) * 3 + (wi2 < 49 ? 0 : (wi2 < 53 ? 1 : 2));
      }
      float vals[4];
      #pragma unroll
      for (int nj = 0; nj < 4; ++nj) {
        const int j = nj * 16 + fr;
        const int r2 = j / 7, c2 = j - r2 * 7;
        int ridx = (r1 - r2 + 6) * 13 + (c1 - c2 + 6);
        ridx = min(max(ridx, 0), 168);
        float v = s_acc[nj][rr] * 0.20412414523193154f + rel[ridx * 8 + h];
        if (shift) {
          const int hj = hblk * 7 + r2, wj = wblk * 7 + c2;
          const int rj = (hj < 49 ? 0 : (hj < 53 ? 1 : 2)) * 3 + (wj < 49 ? 0 : (wj < 53 ? 1 : 2));
          if (ri != rj) v -= 100.f;
        }
        vals[nj] = (j < 49) ? v : -1e30f;
      }
      float mx = fmaxf(fmaxf(vals[0], vals[1]), fmaxf(vals[2], vals[3]));
      #pragma unroll
      for (int off = 8; off >= 1; off >>= 1) mx = fmaxf(mx, __shfl_xor(mx, off));
      float e0 = __expf(vals[0] - mx), e1 = __expf(vals[1] - mx);
      float e2 = __expf(vals[2] - mx), e3 = __expf(vals[3] - mx);
      float sum = e0 + e1 + e2 + e3;
      #pragma unroll
      for (int off = 8; off >= 1; off >>= 1) sum += __shfl_xor(sum, off);
      const float inv = 1.f / sum;
      const int sw = (i & 7) << 4;
      Pw[(i * 128 + (((fr * 2 +   0) ) ^ sw)) >> 1] = f2bf(e0 * inv);
      Pw[(i * 128 + (((fr * 2 +  32) ) ^ sw)) >> 1] = f2bf(e1 * inv);
      Pw[(i * 128 + (((fr * 2 +  64) ) ^ sw)) >> 1] = f2bf(e2 * inv);
      Pw[(i * 128 + (((fr * 2 +  96) ) ^ sw)) >> 1] = f2bf(e3 * inv);
    }
  }

  // PV: O = P(64x64) * V^T(rows d)
  short8 bvf[2][2];
  #pragma unroll
  for (int nd = 0; nd < 2; ++nd)
    #pragma unroll
    for (int kj = 0; kj < 2; ++kj) {
      const int row = wid * 32 + nd * 16 + fr;
      bvf[nd][kj] = *(const short8*)(VT +
          ((row * 128 + ((kj * 64 + fg * 16) ^ (((row >> 2) & 7) << 4))) >> 1));
    }
  #pragma unroll
  for (int mi = 0; mi < 4; ++mi) {
    const int row = mi * 16 + fr;
    short8 pa[2];
    #pragma unroll
    for (int kj = 0; kj < 2; ++kj)
      pa[kj] = *(const short8*)(Pw +
          ((row * 128 + ((kj * 64 + fg * 16) ^ ((row & 7) << 4))) >> 1));
    f32x4 o0 = {0, 0, 0, 0}, o1 = {0, 0, 0, 0};
    o0 = __builtin_amdgcn_mfma_f32_16x16x32_bf16(pa[0], bvf[0][0], o0, 0, 0, 0);
    o0 = __builtin_amdgcn_mfma_f32_16x16x32_bf16(pa[1], bvf[0][1], o0, 0, 0, 0);
    o1 = __builtin_amdgcn_mfma_f32_16x16x32_bf16(pa[0], bvf[1][0], o1, 0, 0, 0);
    o1 = __builtin_amdgcn_mfma_f32_16x16x32_bf16(pa[1], bvf[1][1], o1, 0, 0, 0);
    // store rows i<49, d<24
    #pragma unroll
    for (int rr = 0; rr < 4; ++rr) {
      const int i = mi * 16 + fg * 4 + rr;
      if (i < 49) {
        u16* orow = outp + ((size_t)win * 49 + i) * 192 + h * 24;
        orow[fr] = f2bf(o0[rr]);                   // d = fr (0..15)
        if (fr < 8) orow[16 + fr] = f2bf(o1[rr]);  // d = 16+fr
      }
    }
  }
}

// win-reverse + roll(+shift) + residual add (bf16 src) into f32 act
__global__ __launch_bounds__(256) void winrev_add_k(
    float* __restrict__ act, const u16* __restrict__ pin, int shift)
{
  const int t = blockIdx.x * 4 + (threadIdx.x >> 6);
  const int lane = threadIdx.x & 63;
  const int win = t / 49, within = t - win * 49;
  const int b = win >> 6, wb = win & 63;
  int y = (wb >> 3) * 7 + within / 7 + shift; if (y >= IMG) y -= IMG;
  int x = (wb & 7) * 7 + within % 7 + shift; if (x >= IMG) x -= IMG;
  float* dst = act + ((size_t)b * HW_ + y * IMG + x) * C_DIM;
  const u16* src = pin + (size_t)t * C_DIM;
  dst[lane]       += bf2f(src[lane]);
  dst[lane + 64]  += bf2f(src[lane + 64]);
  dst[lane + 128] += bf2f(src[lane + 128]);
}

// NHWC f32 tokens -> NCHW f32 (ds2 output)
__global__ __launch_bounds__(256) void transpose_k(
    const float* __restrict__ in, float* __restrict__ outp)
{
  __shared__ float tile[32][33];
  const int p0 = blockIdx.x * 32;
  const int c0 = blockIdx.y * 32;
  const int tid = threadIdx.x;
  #pragma unroll
  for (int it = 0; it < 4; ++it) {
    const int id = tid + it * 256;
    const int r = id >> 5, cc = id & 31;
    tile[r][cc] = in[(size_t)(p0 + r) * C_DIM + c0 + cc];
  }
  __syncthreads();
  const int b = p0 / HW_, pp0 = p0 - b * HW_;
  #pragma unroll
  for (int it = 0; it < 4; ++it) {
    const int id = tid + it * 256;
    const int cl = id >> 5, pl = id & 31;
    outp[((size_t)b * C_DIM + c0 + cl) * HW_ + pp0 + pl] = tile[pl][cl];
  }
}

// NCHW f32 -> token-major bf16
__global__ __launch_bounds__(256) void tok_k(
    const float* __restrict__ in, u16* __restrict__ outp)
{
  __shared__ float tile[32][33];
  const int t0 = blockIdx.x * 32;
  const int c0 = blockIdx.y * 32;
  const int tid = threadIdx.x;
  const int b = t0 / HW_, p0 = t0 - b * HW_;
  #pragma unroll
  for (int it = 0; it < 4; ++it) {
    const int id = tid + it * 256;
    const int cl = id >> 5, pl = id & 31;
    tile[cl][pl] = in[((size_t)b * C_DIM + c0 + cl) * HW_ + p0 + pl];
  }
  __syncthreads();
  #pragma unroll
  for (int it = 0; it < 4; ++it) {
    const int id = tid + it * 256;
    const int r = id >> 5, cc = id & 31;
    outp[(size_t)(t0 + r) * C_DIM + c0 + cc] = f2bf(tile[cc][r]);
  }
}

// flat f32 -> bf16 (vectorized x4)
__global__ __launch_bounds__(256) void cvt_k(
    const float* __restrict__ in, u16* __restrict__ outp, int n4)
{
  const int i = blockIdx.x * 256 + threadIdx.x;
  if (i >= n4) return;
  const float4 v = ((const float4*)in)[i];
  u32 lo = (u32)f2bf(v.x) | ((u32)f2bf(v.y) << 16);
  u32 hi = (u32)f2bf(v.z) | ((u32)f2bf(v.w) << 16);
  ((uint2*)outp)[i] = make_uint2(lo, hi);
}

// conv weight (OC,IC,3,3) f32 -> [OCpad][9*192] bf16 (im2col row-major)
__global__ __launch_bounds__(256) void cvtconv_k(
    const float* __restrict__ src, u16* __restrict__ dst, int OC, int OCpad)
{
  const int idx = blockIdx.x * 256 + threadIdx.x;
  if (idx >= OCpad * 1728) return;
  const int n = idx / 1728, kkk = idx - n * 1728;
  const int s = kkk / C_DIM, ic = kkk - s * C_DIM;
  dst[idx] = (n < OC) ? f2bf(src[((size_t)n * C_DIM + ic) * 9 + s]) : (u16)0;
}

// ---------------------------------------------------------------------------
extern "C" void kernel_launch(void* const* d_in, const int* in_sizes, int n_in,
                              void* d_out, int out_size, void* d_ws, size_t ws_size,
                              hipStream_t stream)
{
  const float* x       = (const float*)d_in[0];
  const float* pos     = (const float*)d_in[1];
  const float* proj_w  = (const float*)d_in[2];
  const float* proj_b  = (const float*)d_in[3];
  const float* pe_g    = (const float*)d_in[4];
  const float* pe_b    = (const float*)d_in[5];
  const float* n1_g    = (const float*)d_in[6];
  const float* n1_b    = (const float*)d_in[7];
  const float* qkv_w   = (const float*)d_in[8];
  const float* qkv_b   = (const float*)d_in[9];
  const float* attn_pw = (const float*)d_in[10];
  const float* attn_pb = (const float*)d_in[11];
  const float* rel_tab = (const float*)d_in[12];
  const float* n2_g    = (const float*)d_in[13];
  const float* n2_b    = (const float*)d_in[14];
  const float* fc1_w   = (const float*)d_in[15];
  const float* fc1_b   = (const float*)d_in[16];
  const float* fc2_w   = (const float*)d_in[17];
  const float* fc2_b   = (const float*)d_in[18];
  const float* c1_w    = (const float*)d_in[19];
  const float* c1_b    = (const float*)d_in[20];
  const float* bn1_g   = (const float*)d_in[21];
  const float* bn1_b   = (const float*)d_in[22];
  const float* bn1_m   = (const float*)d_in[23];
  const float* bn1_v   = (const float*)d_in[24];
  const float* c2_w    = (const float*)d_in[25];
  const float* c2_b    = (const float*)d_in[26];
  const float* bn2_g   = (const float*)d_in[27];
  const float* bn2_b   = (const float*)d_in[28];
  const float* bn2_m   = (const float*)d_in[29];
  const float* bn2_v   = (const float*)d_in[30];
  float* out = (float*)d_out;

  const size_t BUF  = (size_t)NTOK * C_DIM * 4;   // 38,535,168 B
  const size_t BIGB = (size_t)NTOK * 576 * 2;     // 57,802,752 B
  char* ws = (char*)d_ws;
  float* act   = (float*)ws;
  u16*   big16 = (u16*)(ws + BUF);
  float* big32 = (float*)(ws + BUF);
  u16*   xln   = (u16*)(ws + BUF + BIGB);
  u16* attn_out = (u16*)d_out;
  u16* wbf = (u16*)((char*)d_out + (size_t)CONV_OUT_SZ * 4);

  const size_t O_QKV = 0;
  const size_t O_FC1 = O_QKV + (size_t)4 * 576 * 192;
  const size_t O_FC2 = O_FC1 + (size_t)4 * 768 * 192;
  const size_t O_PW  = O_FC2 + (size_t)4 * 192 * 768;
  const size_t O_PROJ= O_PW  + (size_t)4 * 192 * 192;
  const size_t O_C1  = O_PROJ+ (size_t)192 * 192;
  const size_t O_C2  = O_C1  + (size_t)192 * 1728;

  const dim3 blk(256);

  cvt_k<<<(4*576*192/4 + 255)/256, blk, 0, stream>>>(qkv_w,   wbf + O_QKV, 4*576*192/4);
  cvt_k<<<(4*768*192/4 + 255)/256, blk, 0, stream>>>(fc1_w,   wbf + O_FC1, 4*768*192/4);
  cvt_k<<<(4*192*768/4 + 255)/256, blk, 0, stream>>>(fc2_w,   wbf + O_FC2, 4*192*768/4);
  cvt_k<<<(4*192*192/4 + 255)/256, blk, 0, stream>>>(attn_pw, wbf + O_PW,  4*192*192/4);
  cvt_k<<<(192*192/4   + 255)/256, blk, 0, stream>>>(proj_w,  wbf + O_PROJ, 192*192/4);
  cvtconv_k<<<(192*1728 + 255)/256, blk, 0, stream>>>(c1_w, wbf + O_C1, 192, 192);
  cvtconv_k<<<(128*1728 + 255)/256, blk, 0, stream>>>(c2_w, wbf + O_C2, 96, 128);

  tok_k<<<dim3(1568, 6), blk, 0, stream>>>(x, xln);
  gmm<0, 5><<<dim3(392, 3), blk, 0, stream>>>(
      xln, wbf + O_PROJ, proj_b, big32, NTOK, 192, 192, nullptr, nullptr, nullptr, nullptr);
  ln_k<float><<<12544, blk, 0, stream>>>(big32, act, pe_g, pe_b, pos, 0, 0);

  for (int i = 0; i < 4; ++i) {
    const int shift = (i & 1) ? 3 : 0;
    ln_k<u16><<<12544, blk, 0, stream>>>(act, xln, n1_g + i * 192, n1_b + i * 192,
                                         nullptr, 1, shift);
    gmm<0, 0><<<dim3(392, 9), blk, 0, stream>>>(
        xln, wbf + O_QKV + (size_t)i * 576 * 192, qkv_b + i * 576, big16,
        NTOK, 576, 192, nullptr, nullptr, nullptr, nullptr);
    attn_m<<<2048, blk, 0, stream>>>(big16, attn_out, rel_tab + i * 169 * 8, shift);
    gmm<0, 0><<<dim3(392, 3), blk, 0, stream>>>(
        attn_out, wbf + O_PW + (size_t)i * 192 * 192, attn_pb + i * 192, xln,
        NTOK, 192, 192, nullptr, nullptr, nullptr, nullptr);
    winrev_add_k<<<12544, blk, 0, stream>>>(act, xln, shift);
    ln_k<u16><<<12544, blk, 0, stream>>>(act, xln, n2_g + i * 192, n2_b + i * 192,
                                         nullptr, 0, 0);
    for (int c = 0; c < 2; ++c) {
      gmm<0, 1><<<dim3(196, 12), blk, 0, stream>>>(
          xln + (size_t)c * 25088 * 192, wbf + O_FC1 + (size_t)i * 768 * 192,
          fc1_b + i * 768, big16, 25088, 768, 192, nullptr, nullptr, nullptr, nullptr);
      gmm<0, 2><<<dim3(196, 3), blk, 0, stream>>>(
          big16, wbf + O_FC2 + (size_t)i * 192 * 768, fc2_b + i * 192,
          act + (size_t)c * 25088 * 192, 25088, 192, 768, nullptr, nullptr, nullptr, nullptr);
    }
  }

  cvt_k<<<(NTOK * C_DIM / 4 + 255)/256, blk, 0, stream>>>(act, xln, NTOK * C_DIM / 4);
  gmm<1, 3><<<dim3(392, 3), blk, 0, stream>>>(
      xln, wbf + O_C1, c1_b, big16, NTOK, 192, 1728, bn1_g, bn1_b, bn1_m, bn1_v);
  gmm<1, 4><<<dim3(392, 2), blk, 0, stream>>>(
      big16, wbf + O_C2, c2_b, out, NTOK, 96, 1728, bn2_g, bn2_b, bn2_m, bn2_v);
  transpose_k<<<dim3(1568, 6), blk, 0, stream>>>(act, out + CONV_OUT_SZ);
}

// Round 6
// 927.816 us; speedup vs baseline: 5.4340x; 1.1872x over previous
//
#include <hip/hip_runtime.h>
#include <math.h>

typedef unsigned short u16;
typedef unsigned int u32;
typedef __attribute__((ext_vector_type(8))) short short8;
typedef __attribute__((ext_vector_type(4))) float f32x4;

#define IMG 56
#define HW_ 3136
#define NTOK 50176
#define C_DIM 192
#define CONV_OUT_SZ 4816896  /* 16*96*3136 floats */

__device__ inline float bf2f(u16 v) {
  u32 u = ((u32)v) << 16; float f; __builtin_memcpy(&f, &u, 4); return f;
}
__device__ inline u16 f2bf(float f) {
  u32 u; __builtin_memcpy(&u, &f, 4);
  u += 0x7FFF + ((u >> 16) & 1);
  return (u16)(u >> 16);
}
__device__ inline void glds16(const u16* g, u16* l) {
  __builtin_amdgcn_global_load_lds((const __attribute__((address_space(1))) u32*)g,
                                   (__attribute__((address_space(3))) u32*)l, 16, 0, 0);
}
__device__ inline u32 pk_bf16(float a, float b) {
  u32 r;
  asm("v_cvt_pk_bf16_f32 %0, %1, %2" : "=v"(r) : "v"(a), "v"(b));
  return r;
}

// ---------------------------------------------------------------------------
// MFMA bf16 GEMM: C[m,n] = epi( sum_k A[m,k]*W[n,k] + bias[n] )
// BM=128, BN=64, BK=64, 256 threads (4 waves, 2x2), 16x16x32 MFMA.
// EPI: 0 store bf16, 1 gelu->bf16, 2 +=f32, 3 BN+relu->bf16 NHWC,
//      4 BN+relu->f32 NCHW (guard c<N), 5 store f32,
//      6 win-reverse + roll(+shiftp) scatter-add into f32 NHWC act.
// ---------------------------------------------------------------------------
template<int AMODE, int EPI>
__global__ __launch_bounds__(256) void gmm(
    const u16* __restrict__ A, const u16* __restrict__ W,
    const float* __restrict__ bias, void* __restrict__ Cout,
    int M, int N, int K,
    const float* __restrict__ bg, const float* __restrict__ bb,
    const float* __restrict__ bm, const float* __restrict__ bv, int shiftp)
{
  __shared__ u16 As[128 * 64];
  __shared__ u16 Bs[64 * 64];
  const int tid = threadIdx.x;
  const int m0 = blockIdx.x * 128, n0 = blockIdx.y * 64;
  const int lane = tid & 63, wid = tid >> 6;
  const int wm = (wid >> 1) * 64, wn = (wid & 1) * 32;
  const int fr = lane & 15, fg = lane >> 4;
  f32x4 acc[4][2] = {};

  for (int kc = 0; kc < K; kc += 64) {
    #pragma unroll
    for (int it = 0; it < 2; ++it) {
      const int g = it * 256 + tid;
      const int row = g >> 3, cb = (g & 7) << 4;
      const int sc = cb ^ ((row & 7) << 4);
      glds16(W + (size_t)(n0 + row) * K + kc + (sc >> 1), Bs + g * 8);
    }
    if (AMODE == 0) {
      #pragma unroll
      for (int it = 0; it < 4; ++it) {
        const int g = it * 256 + tid;
        const int row = g >> 3, cb = (g & 7) << 4;
        const int sc = cb ^ ((row & 7) << 4);
        glds16(A + (size_t)(m0 + row) * K + kc + (sc >> 1), As + g * 8);
      }
    } else {
      #pragma unroll
      for (int it = 0; it < 4; ++it) {
        const int g = it * 256 + tid;
        const int row = g >> 3, cb = (g & 7) << 4;
        const int m = m0 + row;
        const int b = m / HW_, pp = m - b * HW_;
        const int y = pp / IMG, x = pp - (pp / IMG) * IMG;
        const int kg = kc + (cb >> 1);
        const int s = kg / C_DIM, ic = kg - s * C_DIM;
        const int yy = y + s / 3 - 1, xx = x + (s % 3) - 1;
        short8 v = {0, 0, 0, 0, 0, 0, 0, 0};
        if ((unsigned)yy < IMG && (unsigned)xx < IMG)
          v = *(const short8*)(A + ((size_t)(b * HW_ + yy * IMG + xx)) * C_DIM + ic);
        *(short8*)(As + row * 64 + ((cb ^ ((row & 7) << 4)) >> 1)) = v;
      }
    }
    __syncthreads();
    #pragma unroll
    for (int ks = 0; ks < 2; ++ks) {
      const int kb = ks * 64 + fg * 16;
      short8 af[4], bf[2];
      #pragma unroll
      for (int i = 0; i < 4; ++i) {
        const int row = wm + i * 16 + fr;
        af[i] = *(const short8*)(As + ((row * 128 + (kb ^ ((row & 7) << 4))) >> 1));
      }
      #pragma unroll
      for (int j = 0; j < 2; ++j) {
        const int row = wn + j * 16 + fr;
        bf[j] = *(const short8*)(Bs + ((row * 128 + (kb ^ ((row & 7) << 4))) >> 1));
      }
      #pragma unroll
      for (int i = 0; i < 4; ++i)
        #pragma unroll
        for (int j = 0; j < 2; ++j)
          acc[i][j] = __builtin_amdgcn_mfma_f32_16x16x32_bf16(af[i], bf[j], acc[i][j], 0, 0, 0);
    }
    __syncthreads();
  }

  const int c0 = n0 + wn + fr;
  const int c1i = (EPI == 4) ? min(c0 + 16, N - 1) : (c0 + 16);
  const float bias0 = bias[c0], bias1 = bias[c1i];
  float s0 = 0.f, h0 = 0.f, s1 = 0.f, h1 = 0.f;
  if (EPI == 3 || EPI == 4) {
    s0 = bg[c0] * rsqrtf(bv[c0] + 1e-5f); h0 = bb[c0] - bm[c0] * s0;
    s1 = bg[c1i] * rsqrtf(bv[c1i] + 1e-5f); h1 = bb[c1i] - bm[c1i] * s1;
  }
  #pragma unroll
  for (int i = 0; i < 4; ++i) {
    #pragma unroll
    for (int r = 0; r < 4; ++r) {
      const int m = m0 + wm + i * 16 + fg * 4 + r;
      size_t sbase = 0;
      if (EPI == 6) {
        const int wno = m / 49, within = m - wno * 49;
        const int b2 = wno >> 6, wb3 = wno & 63;
        const int wr = within / 7, wc = within - wr * 7;
        int y2 = (wb3 >> 3) * 7 + wr + shiftp; if (y2 >= IMG) y2 -= IMG;
        int x2 = (wb3 & 7) * 7 + wc + shiftp; if (x2 >= IMG) x2 -= IMG;
        sbase = ((size_t)(b2 * HW_ + y2 * IMG + x2)) * C_DIM;
      }
      #pragma unroll
      for (int j = 0; j < 2; ++j) {
        const int c = c0 + j * 16;
        float v = acc[i][j][r] + (j ? bias1 : bias0);
        if (EPI == 1) v = 0.5f * v * (1.f + erff(v * 0.70710678118f));
        if (EPI == 3 || EPI == 4) { v = v * (j ? s1 : s0) + (j ? h1 : h0); v = fmaxf(v, 0.f); }
        if (EPI == 0 || EPI == 1 || EPI == 3) {
          ((u16*)Cout)[(size_t)m * N + c] = f2bf(v);
        } else if (EPI == 5) {
          ((float*)Cout)[(size_t)m * N + c] = v;
        } else if (EPI == 2) {
          ((float*)Cout)[(size_t)m * N + c] += v;
        } else if (EPI == 6) {
          ((float*)Cout)[sbase + c] += v;
        } else {  // EPI 4
          if (c < N) {
            const int b = m / HW_, pp = m - b * HW_;
            ((float*)Cout)[((size_t)b * N + c) * HW_ + pp] = v;
          }
        }
      }
    }
  }
}

// ---------------------------------------------------------------------------
__device__ inline void stv(float* p, float v) { *p = v; }
__device__ inline void stv(u16* p, float v) { *p = f2bf(v); }

template<typename OT>
__global__ __launch_bounds__(256) void ln_k(
    const float* __restrict__ in, OT* __restrict__ outp,
    const float* __restrict__ g, const float* __restrict__ bta,
    const float* __restrict__ pos, int winpart, int shift)
{
  const int t = blockIdx.x * 4 + (threadIdx.x >> 6);
  const int lane = threadIdx.x & 63;
  const float* xr = in + (size_t)t * C_DIM;
  const float v0 = xr[lane], v1 = xr[lane + 64], v2 = xr[lane + 128];
  float s = v0 + v1 + v2;
  float ss = v0 * v0 + v1 * v1 + v2 * v2;
  #pragma unroll
  for (int off = 32; off > 0; off >>= 1) {
    s += __shfl_xor(s, off);
    ss += __shfl_xor(ss, off);
  }
  const float mean = s * (1.f / 192.f);
  const float inv = rsqrtf(ss * (1.f / 192.f) - mean * mean + 1e-5f);
  const int b = t / HW_, pp = t - b * HW_;
  size_t obase;
  if (winpart) {
    const int y = pp / IMG, x = pp - (pp / IMG) * IMG;
    int yr = y - shift; if (yr < 0) yr += IMG;
    int xs = x - shift; if (xs < 0) xs += IMG;
    const int win = b * 64 + (yr / 7) * 8 + (xs / 7);
    const int within = (yr % 7) * 7 + (xs % 7);
    obase = ((size_t)win * 49 + within) * C_DIM;
  } else {
    obase = (size_t)t * C_DIM;
  }
  OT* o = outp + obase;
  float p0 = 0.f, p1 = 0.f, p2 = 0.f;
  if (pos) {
    const float* pr = pos + (size_t)pp * C_DIM;
    p0 = pr[lane]; p1 = pr[lane + 64]; p2 = pr[lane + 128];
  }
  stv(o + lane,       (v0 - mean) * inv * g[lane]       + bta[lane]       + p0);
  stv(o + lane + 64,  (v1 - mean) * inv * g[lane + 64]  + bta[lane + 64]  + p1);
  stv(o + lane + 128, (v2 - mean) * inv * g[lane + 128] + bta[lane + 128] + p2);
}

// ---------------------------------------------------------------------------
// MFMA window attention, swapped-QK^T + sigma-order PV (P stays in registers).
// Block = 4 waves; wave = one (window, head). win = bid>>1, heads (bid&1)*4+wid.
// ---------------------------------------------------------------------------
template<int SHIFT>
__global__ __launch_bounds__(256) void attn_m(
    const u16* __restrict__ qkv, u16* __restrict__ outp,
    const float* __restrict__ rel)
{
  __shared__ u16 VT[128 * 64];          // V^T rows d' = wid*32+dl, swz key (row>>2)&7
  __shared__ float relS[4 * 176 + 16];  // per-head rel table
  const int tid = threadIdx.x;
  const int wid = tid >> 6, lane = tid & 63;
  const int fr = lane & 15, fg = lane >> 4;
  const int win = blockIdx.x >> 1;
  const int hb = blockIdx.x & 1;
  const int h = hb * 4 + wid;
  const u16* wbase = qkv + (size_t)win * 49 * 576;

  {
    u32* vz = (u32*)VT;
    #pragma unroll
    for (int it = 0; it < 16; ++it) vz[it * 256 + tid] = 0;
  }
  for (int id = tid; id < 169 * 4; id += 256) {
    const int hl = id & 3, ridx = id >> 2;
    relS[hl * 176 + ridx] = rel[ridx * 8 + hb * 4 + hl];
  }
  __syncthreads();
  for (int id = tid; id < 49 * 24; id += 256) {
    const int j = id / 24, dq = id - (id / 24) * 24;
    const int dd = dq * 4;
    const uint2 v = *(const uint2*)(wbase + j * 576 + 384 + hb * 96 + dd);
    const u16* pv = (const u16*)&v;
    const int wpr = dd / 24, dl = dd - wpr * 24;
    #pragma unroll
    for (int e = 0; e < 4; ++e) {
      const int row = wpr * 32 + dl + e;
      VT[(row * 128 + ((j * 2) ^ (((row >> 2) & 7) << 4))) >> 1] = pv[e];
    }
  }
  __syncthreads();

  // Q/K fragments: lane(fr,fg) holds row t*16+fr, d = fg*8..+7 (fg==3 zero pad)
  short8 qf[4], kf[4];
  #pragma unroll
  for (int t = 0; t < 4; ++t) {
    const int row = t * 16 + fr;
    if (fg < 3) {
      qf[t] = *(const short8*)(wbase + row * 576 + h * 24 + fg * 8);
      kf[t] = *(const short8*)(wbase + row * 576 + 192 + h * 24 + fg * 8);
    } else {
      qf[t] = (short8){0, 0, 0, 0, 0, 0, 0, 0};
      kf[t] = (short8){0, 0, 0, 0, 0, 0, 0, 0};
    }
  }

  // V^T A-fragments in sigma order: slot (fg,e) = V^T[db*16+fr][(2ks+(e>>2))*16+fg*4+(e&3)]
  short8 av[2][2];
  #pragma unroll
  for (int db = 0; db < 2; ++db) {
    const int row = wid * 32 + db * 16 + fr;
    const int swz = ((row >> 2) & 7) << 4;
    #pragma unroll
    for (int ks = 0; ks < 2; ++ks) {
      const uint2 lo = *(const uint2*)((const char*)VT + row * 128 + (((2 * ks) * 32 + fg * 8) ^ swz));
      const uint2 hi = *(const uint2*)((const char*)VT + row * 128 + (((2 * ks + 1) * 32 + fg * 8) ^ swz));
      u32 w[4] = {lo.x, lo.y, hi.x, hi.y};
      av[db][ks] = *(short8*)w;
    }
  }

  const int wb2 = win & 63;
  const int hblk = wb2 >> 3, wblk = wb2 & 7;

  // per-lane key-side geometry, packed (j = nj*16 + fg*4 + r)
  u32 joffPk[4];
  u32 jregPk[2] = {0, 0};
  #pragma unroll
  for (int nj = 0; nj < 4; ++nj) {
    u32 w = 0;
    #pragma unroll
    for (int r = 0; r < 4; ++r) {
      const int j = nj * 16 + fg * 4 + r;
      const int r2 = j / 7, c2 = j - r2 * 7;
      w |= (u32)(r2 * 13 + c2) << (r * 8);
      if (SHIFT) {
        const int hj = hblk * 7 + r2, wj = wblk * 7 + c2;
        const int rj = (hj < 49 ? 0 : (hj < 53 ? 1 : 2)) * 3 + (wj < 49 ? 0 : (wj < 53 ? 1 : 2));
        jregPk[nj >> 1] |= (u32)rj << (((nj & 1) * 4 + r) * 4);
      }
    }
    joffPk[nj] = w;
  }

  const float* relw = relS + wid * 176;
  const float scl = 0.20412414523193154f;

  #pragma unroll
  for (int mi = 0; mi < 4; ++mi) {
    f32x4 sacc[4];
    #pragma unroll
    for (int nj = 0; nj < 4; ++nj)
      sacc[nj] = __builtin_amdgcn_mfma_f32_16x16x32_bf16(kf[nj], qf[mi],
                                                         (f32x4){0, 0, 0, 0}, 0, 0, 0);
    const int i = mi * 16 + fr;
    const int r1 = i / 7, c1 = i - r1 * 7;
    const int base13 = (r1 + 6) * 13 + (c1 + 6);
    int ri = 0;
    if (SHIFT) {
      const int hi2 = hblk * 7 + r1, wi2 = wblk * 7 + c1;
      ri = (hi2 < 49 ? 0 : (hi2 < 53 ? 1 : 2)) * 3 + (wi2 < 49 ? 0 : (wi2 < 53 ? 1 : 2));
    }
    float p[16];
    float mx = -1e30f;
    #pragma unroll
    for (int nj = 0; nj < 4; ++nj) {
      #pragma unroll
      for (int r = 0; r < 4; ++r) {
        const int j = nj * 16 + fg * 4 + r;
        int idx = base13 - (int)((joffPk[nj] >> (r * 8)) & 0xff);
        idx = min(max(idx, 0), 168);
        float v = sacc[nj][r] * scl + relw[idx];
        if (SHIFT) {
          const int rj = (jregPk[nj >> 1] >> (((nj & 1) * 4 + r) * 4)) & 0xf;
          v = (ri != rj) ? v - 100.f : v;
        }
        v = (j < 49) ? v : -1e30f;
        p[nj * 4 + r] = v;
        mx = fmaxf(mx, v);
      }
    }
    mx = fmaxf(mx, __shfl_xor(mx, 16));
    mx = fmaxf(mx, __shfl_xor(mx, 32));
    float sum = 0.f;
    #pragma unroll
    for (int e = 0; e < 16; ++e) { p[e] = __expf(p[e] - mx); sum += p[e]; }
    sum += __shfl_xor(sum, 16);
    sum += __shfl_xor(sum, 32);
    const float inv = 1.f / sum;
    // P -> sigma-order B-fragments, fully in-register
    short8 pb[2];
    #pragma unroll
    for (int ks = 0; ks < 2; ++ks) {
      u32 w[4];
      #pragma unroll
      for (int half = 0; half < 2; ++half) {
        const int nj = 2 * ks + half;
        w[half * 2 + 0] = pk_bf16(p[nj * 4 + 0] * inv, p[nj * 4 + 1] * inv);
        w[half * 2 + 1] = pk_bf16(p[nj * 4 + 2] * inv, p[nj * 4 + 3] * inv);
      }
      pb[ks] = *(short8*)w;
    }
    // PV: D[d][i]
    f32x4 o0 = {0, 0, 0, 0}, o1 = {0, 0, 0, 0};
    o0 = __builtin_amdgcn_mfma_f32_16x16x32_bf16(av[0][0], pb[0], o0, 0, 0, 0);
    o0 = __builtin_amdgcn_mfma_f32_16x16x32_bf16(av[0][1], pb[1], o0, 0, 0, 0);
    o1 = __builtin_amdgcn_mfma_f32_16x16x32_bf16(av[1][0], pb[0], o1, 0, 0, 0);
    o1 = __builtin_amdgcn_mfma_f32_16x16x32_bf16(av[1][1], pb[1], o1, 0, 0, 0);
    // store: lane(fr,fg): O[i][d = db*16 + fg*4 + 0..3], packed 8B
    if (i < 49) {
      u16* orow = outp + ((size_t)win * 49 + i) * C_DIM + h * 24;
      *(uint2*)(orow + fg * 4) =
          make_uint2(pk_bf16(o0[0], o0[1]), pk_bf16(o0[2], o0[3]));
      if (fg < 2)
        *(uint2*)(orow + 16 + fg * 4) =
            make_uint2(pk_bf16(o1[0], o1[1]), pk_bf16(o1[2], o1[3]));
    }
  }
}

// NHWC f32 tokens -> NCHW f32 (ds2 output)
__global__ __launch_bounds__(256) void transpose_k(
    const float* __restrict__ in, float* __restrict__ outp)
{
  __shared__ float tile[32][33];
  const int p0 = blockIdx.x * 32;
  const int c0 = blockIdx.y * 32;
  const int tid = threadIdx.x;
  #pragma unroll
  for (int it = 0; it < 4; ++it) {
    const int id = tid + it * 256;
    const int r = id >> 5, cc = id & 31;
    tile[r][cc] = in[(size_t)(p0 + r) * C_DIM + c0 + cc];
  }
  __syncthreads();
  const int b = p0 / HW_, pp0 = p0 - b * HW_;
  #pragma unroll
  for (int it = 0; it < 4; ++it) {
    const int id = tid + it * 256;
    const int cl = id >> 5, pl = id & 31;
    outp[((size_t)b * C_DIM + c0 + cl) * HW_ + pp0 + pl] = tile[pl][cl];
  }
}

// NCHW f32 -> token-major bf16
__global__ __launch_bounds__(256) void tok_k(
    const float* __restrict__ in, u16* __restrict__ outp)
{
  __shared__ float tile[32][33];
  const int t0 = blockIdx.x * 32;
  const int c0 = blockIdx.y * 32;
  const int tid = threadIdx.x;
  const int b = t0 / HW_, p0 = t0 - b * HW_;
  #pragma unroll
  for (int it = 0; it < 4; ++it) {
    const int id = tid + it * 256;
    const int cl = id >> 5, pl = id & 31;
    tile[cl][pl] = in[((size_t)b * C_DIM + c0 + cl) * HW_ + p0 + pl];
  }
  __syncthreads();
  #pragma unroll
  for (int it = 0; it < 4; ++it) {
    const int id = tid + it * 256;
    const int r = id >> 5, cc = id & 31;
    outp[(size_t)(t0 + r) * C_DIM + c0 + cc] = f2bf(tile[cc][r]);
  }
}

// flat f32 -> bf16 (vectorized x4)
__global__ __launch_bounds__(256) void cvt_k(
    const float* __restrict__ in, u16* __restrict__ outp, int n4)
{
  const int i = blockIdx.x * 256 + threadIdx.x;
  if (i >= n4) return;
  const float4 v = ((const float4*)in)[i];
  u32 lo = (u32)f2bf(v.x) | ((u32)f2bf(v.y) << 16);
  u32 hi = (u32)f2bf(v.z) | ((u32)f2bf(v.w) << 16);
  ((uint2*)outp)[i] = make_uint2(lo, hi);
}

// conv weight (OC,IC,3,3) f32 -> [OCpad][9*192] bf16 (im2col row-major)
__global__ __launch_bounds__(256) void cvtconv_k(
    const float* __restrict__ src, u16* __restrict__ dst, int OC, int OCpad)
{
  const int idx = blockIdx.x * 256 + threadIdx.x;
  if (idx >= OCpad * 1728) return;
  const int n = idx / 1728, kkk = idx - n * 1728;
  const int s = kkk / C_DIM, ic = kkk - s * C_DIM;
  dst[idx] = (n < OC) ? f2bf(src[((size_t)n * C_DIM + ic) * 9 + s]) : (u16)0;
}

// ---------------------------------------------------------------------------
extern "C" void kernel_launch(void* const* d_in, const int* in_sizes, int n_in,
                              void* d_out, int out_size, void* d_ws, size_t ws_size,
                              hipStream_t stream)
{
  const float* x       = (const float*)d_in[0];
  const float* pos     = (const float*)d_in[1];
  const float* proj_w  = (const float*)d_in[2];
  const float* proj_b  = (const float*)d_in[3];
  const float* pe_g    = (const float*)d_in[4];
  const float* pe_b    = (const float*)d_in[5];
  const float* n1_g    = (const float*)d_in[6];
  const float* n1_b    = (const float*)d_in[7];
  const float* qkv_w   = (const float*)d_in[8];
  const float* qkv_b   = (const float*)d_in[9];
  const float* attn_pw = (const float*)d_in[10];
  const float* attn_pb = (const float*)d_in[11];
  const float* rel_tab = (const float*)d_in[12];
  const float* n2_g    = (const float*)d_in[13];
  const float* n2_b    = (const float*)d_in[14];
  const float* fc1_w   = (const float*)d_in[15];
  const float* fc1_b   = (const float*)d_in[16];
  const float* fc2_w   = (const float*)d_in[17];
  const float* fc2_b   = (const float*)d_in[18];
  const float* c1_w    = (const float*)d_in[19];
  const float* c1_b    = (const float*)d_in[20];
  const float* bn1_g   = (const float*)d_in[21];
  const float* bn1_b   = (const float*)d_in[22];
  const float* bn1_m   = (const float*)d_in[23];
  const float* bn1_v   = (const float*)d_in[24];
  const float* c2_w    = (const float*)d_in[25];
  const float* c2_b    = (const float*)d_in[26];
  const float* bn2_g   = (const float*)d_in[27];
  const float* bn2_b   = (const float*)d_in[28];
  const float* bn2_m   = (const float*)d_in[29];
  const float* bn2_v   = (const float*)d_in[30];
  float* out = (float*)d_out;

  const size_t BUF  = (size_t)NTOK * C_DIM * 4;   // 38,535,168 B
  const size_t BIGB = (size_t)NTOK * 576 * 2;     // 57,802,752 B
  char* ws = (char*)d_ws;
  float* act   = (float*)ws;
  u16*   big16 = (u16*)(ws + BUF);
  float* big32 = (float*)(ws + BUF);
  u16*   xln   = (u16*)(ws + BUF + BIGB);
  u16* attn_out = (u16*)d_out;
  u16* wbf = (u16*)((char*)d_out + (size_t)CONV_OUT_SZ * 4);

  const size_t O_QKV = 0;
  const size_t O_FC1 = O_QKV + (size_t)4 * 576 * 192;
  const size_t O_FC2 = O_FC1 + (size_t)4 * 768 * 192;
  const size_t O_PW  = O_FC2 + (size_t)4 * 192 * 768;
  const size_t O_PROJ= O_PW  + (size_t)4 * 192 * 192;
  const size_t O_C1  = O_PROJ+ (size_t)192 * 192;
  const size_t O_C2  = O_C1  + (size_t)192 * 1728;

  const dim3 blk(256);

  cvt_k<<<(4*576*192/4 + 255)/256, blk, 0, stream>>>(qkv_w,   wbf + O_QKV, 4*576*192/4);
  cvt_k<<<(4*768*192/4 + 255)/256, blk, 0, stream>>>(fc1_w,   wbf + O_FC1, 4*768*192/4);
  cvt_k<<<(4*192*768/4 + 255)/256, blk, 0, stream>>>(fc2_w,   wbf + O_FC2, 4*192*768/4);
  cvt_k<<<(4*192*192/4 + 255)/256, blk, 0, stream>>>(attn_pw, wbf + O_PW,  4*192*192/4);
  cvt_k<<<(192*192/4   + 255)/256, blk, 0, stream>>>(proj_w,  wbf + O_PROJ, 192*192/4);
  cvtconv_k<<<(192*1728 + 255)/256, blk, 0, stream>>>(c1_w, wbf + O_C1, 192, 192);
  cvtconv_k<<<(128*1728 + 255)/256, blk, 0, stream>>>(c2_w, wbf + O_C2, 96, 128);

  tok_k<<<dim3(1568, 6), blk, 0, stream>>>(x, xln);
  gmm<0, 5><<<dim3(392, 3), blk, 0, stream>>>(
      xln, wbf + O_PROJ, proj_b, big32, NTOK, 192, 192,
      nullptr, nullptr, nullptr, nullptr, 0);
  ln_k<float><<<12544, blk, 0, stream>>>(big32, act, pe_g, pe_b, pos, 0, 0);

  for (int i = 0; i < 4; ++i) {
    const int shift = (i & 1) ? 3 : 0;
    ln_k<u16><<<12544, blk, 0, stream>>>(act, xln, n1_g + i * 192, n1_b + i * 192,
                                         nullptr, 1, shift);
    gmm<0, 0><<<dim3(392, 9), blk, 0, stream>>>(
        xln, wbf + O_QKV + (size_t)i * 576 * 192, qkv_b + i * 576, big16,
        NTOK, 576, 192, nullptr, nullptr, nullptr, nullptr, 0);
    if (shift)
      attn_m<3><<<2048, blk, 0, stream>>>(big16, attn_out, rel_tab + i * 169 * 8);
    else
      attn_m<0><<<2048, blk, 0, stream>>>(big16, attn_out, rel_tab + i * 169 * 8);
    // proj GEMM with fused win-reverse + roll + residual scatter-add into act
    gmm<0, 6><<<dim3(392, 3), blk, 0, stream>>>(
        attn_out, wbf + O_PW + (size_t)i * 192 * 192, attn_pb + i * 192, act,
        NTOK, 192, 192, nullptr, nullptr, nullptr, nullptr, shift);
    ln_k<u16><<<12544, blk, 0, stream>>>(act, xln, n2_g + i * 192, n2_b + i * 192,
                                         nullptr, 0, 0);
    for (int c = 0; c < 2; ++c) {
      gmm<0, 1><<<dim3(196, 12), blk, 0, stream>>>(
          xln + (size_t)c * 25088 * 192, wbf + O_FC1 + (size_t)i * 768 * 192,
          fc1_b + i * 768, big16, 25088, 768, 192,
          nullptr, nullptr, nullptr, nullptr, 0);
      gmm<0, 2><<<dim3(196, 3), blk, 0, stream>>>(
          big16, wbf + O_FC2 + (size_t)i * 192 * 768, fc2_b + i * 192,
          act + (size_t)c * 25088 * 192, 25088, 192, 768,
          nullptr, nullptr, nullptr, nullptr, 0);
    }
  }

  cvt_k<<<(NTOK * C_DIM / 4 + 255)/256, blk, 0, stream>>>(act, xln, NTOK * C_DIM / 4);
  gmm<1, 3><<<dim3(392, 3), blk, 0, stream>>>(
      xln, wbf + O_C1, c1_b, big16, NTOK, 192, 1728, bn1_g, bn1_b, bn1_m, bn1_v, 0);
  gmm<1, 4><<<dim3(392, 2), blk, 0, stream>>>(
      big16, wbf + O_C2, c2_b, out, NTOK, 96, 1728, bn2_g, bn2_b, bn2_m, bn2_v, 0);
  transpose_k<<<dim3(1568, 6), blk, 0, stream>>>(act, out + CONV_OUT_SZ);
}